// Round 3
// baseline (12188.376 us; speedup 1.0000x reference)
//
#include <hip/hip_runtime.h>
#include <cmath>

#define Bn 64
#define Tn 512
#define Dn 400
#define Ln 25
#define Hn 200
#define G4n 800
#define TCn 64
#define NCH 8
#define NPADn 832
#define KSPLIT 4
#define KS 50

// ---- workspace layout (float offsets); total ~85.0 MB ----
constexpr size_t OFF_WIHT = 0;                                  // [2][400][832]
constexpr size_t OFF_BSUM = OFF_WIHT + (size_t)2*Dn*NPADn;      // [2][800]
constexpr size_t OFF_G    = OFF_BSUM + (size_t)2*G4n;           // [2][64][64][800]
constexpr size_t OFF_HCAT = OFF_G + (size_t)2*Bn*TCn*G4n;       // [64][512][400]
constexpr size_t OFF_E    = OFF_HCAT + (size_t)Bn*Tn*2*Hn;      // [64][512][25]
constexpr size_t OFF_HST  = OFF_E + (size_t)Bn*Tn*Ln;           // [2][64][200]
constexpr size_t OFF_CST  = OFF_HST + (size_t)2*Bn*Hn;          // [2][64][200]
constexpr size_t OFF_HX   = OFF_CST + (size_t)2*Bn*Hn;          // [2][32][2slot][2b][200]
constexpr size_t OFF_FLAG = OFF_HX + (size_t)2*32*2*2*Hn;       // [2][32][4][16] ints
constexpr size_t OFF_PART = OFF_FLAG + (size_t)2*32*4*16;       // [64]

__device__ __forceinline__ float sigf(float x) { return 1.0f / (1.0f + expf(-x)); }

// ---------------- prep: transpose/pack weights, zero state+flags ----------------
__global__ void prep_kernel(const float* __restrict__ Wih_f,
                            const float* __restrict__ bih_f, const float* __restrict__ bhh_f,
                            const float* __restrict__ Wih_b,
                            const float* __restrict__ bih_b, const float* __restrict__ bhh_b,
                            float* __restrict__ ws) {
    int tid = blockIdx.x * blockDim.x + threadIdx.x;
    int nth = gridDim.x * blockDim.x;
    float* WihT = ws + OFF_WIHT;
    float* bsum = ws + OFF_BSUM;
    float* hst  = ws + OFF_HST;
    float* cst  = ws + OFF_CST;
    int*   flg  = (int*)(ws + OFF_FLAG);
    for (int i = tid; i < 2*Dn*NPADn; i += nth) {
        int d = i / (Dn*NPADn); int r = i % (Dn*NPADn); int k = r / NPADn; int g = r % NPADn;
        const float* W = d ? Wih_b : Wih_f;
        WihT[i] = (g < G4n) ? W[(size_t)g*Dn + k] : 0.0f;
    }
    for (int i = tid; i < 2*G4n; i += nth) {
        int d = i / G4n; int g = i % G4n;
        bsum[i] = d ? (bih_b[g] + bhh_b[g]) : (bih_f[g] + bhh_f[g]);
    }
    for (int i = tid; i < 2*Bn*Hn; i += nth) { hst[i] = 0.0f; cst[i] = 0.0f; }
    for (int i = tid; i < 2*32*4*16; i += nth) flg[i] = 0;
}

// ---------------- input projection GEMM for one time-chunk (both dirs) ----------------
// grid: (13 N-tiles, 32 b-pairs, 2 dir), 256 threads; BM=128 (2 b x 64 t), BN=64, BK=16
__global__ __launch_bounds__(256) void gemm_kernel(const float* __restrict__ X,
                                                   float* __restrict__ ws, int chunk) {
    const float* WihT = ws + OFF_WIHT;
    const float* bsum = ws + OFF_BSUM;
    float* G = ws + OFF_G;
    int d = blockIdx.z;
    int bp = blockIdx.y;          // batch pair
    int g0 = blockIdx.x * 64;
    int tid = threadIdx.x;
    int tx = tid % 16, ty = tid / 16;
    int t_base = (d == 0) ? chunk * TCn : (Tn - (chunk + 1) * TCn);
    const float* Bmat = WihT + (size_t)d * Dn * NPADn;

    __shared__ float As[16][136];
    __shared__ float Bs[16][68];
    float acc[8][4] = {{0.f}};
    int lr = tid / 2, lk = tid % 2;   // A load: row in [0,128), k-octet
    int bk = tid / 16, bg = tid % 16; // B load: k row, g-quad
    int a_b = bp * 2 + lr / 64;
    int a_t = t_base + (lr % 64);
    const float* Arow = X + ((size_t)a_b * Tn + a_t) * Dn;

    for (int kt = 0; kt < Dn; kt += 16) {
        float4 a4a = *(const float4*)(Arow + kt + lk * 8);
        float4 a4b = *(const float4*)(Arow + kt + lk * 8 + 4);
        float4 b4  = *(const float4*)(Bmat + (size_t)(kt + bk) * NPADn + g0 + bg * 4);
        __syncthreads();
        As[lk*8+0][lr] = a4a.x; As[lk*8+1][lr] = a4a.y;
        As[lk*8+2][lr] = a4a.z; As[lk*8+3][lr] = a4a.w;
        As[lk*8+4][lr] = a4b.x; As[lk*8+5][lr] = a4b.y;
        As[lk*8+6][lr] = a4b.z; As[lk*8+7][lr] = a4b.w;
        *(float4*)&Bs[bk][bg*4] = b4;
        __syncthreads();
        #pragma unroll
        for (int kk = 0; kk < 16; ++kk) {
            float4 af0 = *(const float4*)&As[kk][ty*8];
            float4 af1 = *(const float4*)&As[kk][ty*8+4];
            float4 bf  = *(const float4*)&Bs[kk][tx*4];
            acc[0][0] += af0.x*bf.x; acc[0][1] += af0.x*bf.y; acc[0][2] += af0.x*bf.z; acc[0][3] += af0.x*bf.w;
            acc[1][0] += af0.y*bf.x; acc[1][1] += af0.y*bf.y; acc[1][2] += af0.y*bf.z; acc[1][3] += af0.y*bf.w;
            acc[2][0] += af0.z*bf.x; acc[2][1] += af0.z*bf.y; acc[2][2] += af0.z*bf.z; acc[2][3] += af0.z*bf.w;
            acc[3][0] += af0.w*bf.x; acc[3][1] += af0.w*bf.y; acc[3][2] += af0.w*bf.z; acc[3][3] += af0.w*bf.w;
            acc[4][0] += af1.x*bf.x; acc[4][1] += af1.x*bf.y; acc[4][2] += af1.x*bf.z; acc[4][3] += af1.x*bf.w;
            acc[5][0] += af1.y*bf.x; acc[5][1] += af1.y*bf.y; acc[5][2] += af1.y*bf.z; acc[5][3] += af1.y*bf.w;
            acc[6][0] += af1.z*bf.x; acc[6][1] += af1.z*bf.y; acc[6][2] += af1.z*bf.z; acc[6][3] += af1.z*bf.w;
            acc[7][0] += af1.w*bf.x; acc[7][1] += af1.w*bf.y; acc[7][2] += af1.w*bf.z; acc[7][3] += af1.w*bf.w;
        }
    }
    #pragma unroll
    for (int ii = 0; ii < 8; ++ii) {
        int r = ty * 8 + ii;
        int b = bp * 2 + r / 64;
        int tloc = r % 64;
        #pragma unroll
        for (int jj = 0; jj < 4; ++jj) {
            int g = g0 + tx * 4 + jj;
            if (g < G4n) {
                int k = g % Hn, q = g / Hn;
                G[(((size_t)d*Bn + b)*TCn + tloc)*G4n + k*4 + q] = acc[ii][jj] + bsum[d*G4n + g];
            }
        }
    }
}

// ---------------- LSTM recurrence, k-split x4 across WGs, weights in VGPRs ----------------
// grid: (4 ksplit, 32 pair, 2 dir) = 256 WGs (1/CU), 1024 threads.
// gemv: thread (r = tid%200 -> (kl,q), part = tid/200 in [0,5)) holds W[q*200+k0+kl][part*40..+40] in regs.
// reduce: thread tid<100 -> (kl = tid>>1, b = tid&1) assembles gates, updates h,c.
// exchange: agent-scope atomics + stamped flags between the 4 sibling WGs.
__global__ __launch_bounds__(1024, 4) void rec_kernel(const float* __restrict__ mask,
                                                      const float* __restrict__ Whh_f,
                                                      const float* __restrict__ Whh_b,
                                                      float* __restrict__ ws, int chunk) {
    const float* G = ws + OFF_G;
    float* Hcat = ws + OFF_HCAT;
    float* hst = ws + OFF_HST;
    float* cst = ws + OFF_CST;
    float* hx  = ws + OFF_HX;
    int*   flg = (int*)(ws + OFF_FLAG);

    int ksp  = blockIdx.x;
    int pair = blockIdx.y;
    int d    = blockIdx.z;
    int tid  = threadIdx.x;
    int k0 = ksp * KS;
    const float* Whh = d ? Whh_b : Whh_f;

    int r = tid % 200;
    int part = tid / 200;            // 0..5 (part 5 = 24 idle threads)
    bool gemv_act = (tid < 1000);
    int kl = r >> 2, q = r & 3;

    bool red_act = (tid < 100);
    int rb = tid & 1, rkl = tid >> 1;
    int rbb = pair * 2 + rb;

    __shared__ float hbuf[2][2][208];
    __shared__ float partial[5][2][208];

    // weights -> registers (once)
    float4 wreg[10];
    if (gemv_act) {
        const float* Wrow = Whh + (size_t)(q * Hn + k0 + kl) * Hn + part * 40;
        #pragma unroll
        for (int jj = 0; jj < 10; ++jj) wreg[jj] = *(const float4*)(Wrow + jj * 4);
    }
    // init hbuf (full h for both b) from carry state
    for (int i = tid; i < 2 * Hn; i += 1024) {
        int b = i / Hn, k = i % Hn;
        hbuf[0][b][k] = hst[((size_t)d * Bn + pair * 2 + b) * Hn + k];
    }
    float hr = 0.f, cr = 0.f;
    if (red_act) {
        hr = hst[((size_t)d * Bn + rbb) * Hn + k0 + rkl];
        cr = cst[((size_t)d * Bn + rbb) * Hn + k0 + rkl];
    }
    __syncthreads();

    int cur = 0;
    for (int s = 0; s < TCn; ++s) {
        int tg, tloc;
        if (d == 0) { tloc = s; tg = chunk * TCn + s; }
        else        { tloc = TCn - 1 - s; tg = Tn - 1 - (chunk * TCn + s); }
        int stamp = chunk * TCn + s + 1;
        int slot = stamp & 1;

        float m_ = 0.f; float4 gpre = {0.f, 0.f, 0.f, 0.f};
        if (red_act) {   // prefetch; consumed after barrier
            m_ = mask[(size_t)rbb * Tn + tg];
            gpre = *(const float4*)(G + (((size_t)d * Bn + rbb) * TCn + tloc) * G4n + (k0 + rkl) * 4);
        }
        if (gemv_act) {
            float acc0 = 0.f, acc1 = 0.f;
            #pragma unroll
            for (int jj = 0; jj < 10; ++jj) {
                float4 wv = wreg[jj];
                float4 h0 = *(const float4*)&hbuf[cur][0][part * 40 + jj * 4];
                float4 h1 = *(const float4*)&hbuf[cur][1][part * 40 + jj * 4];
                acc0 += wv.x * h0.x; acc0 += wv.y * h0.y; acc0 += wv.z * h0.z; acc0 += wv.w * h0.w;
                acc1 += wv.x * h1.x; acc1 += wv.y * h1.y; acc1 += wv.z * h1.z; acc1 += wv.w * h1.w;
            }
            partial[part][0][r] = acc0;
            partial[part][1][r] = acc1;
        }
        __syncthreads();
        if (red_act) {
            float g4[4];
            #pragma unroll
            for (int qq = 0; qq < 4; ++qq) {
                int rr = rkl * 4 + qq;
                g4[qq] = ((partial[0][rb][rr] + partial[1][rb][rr]) +
                          (partial[2][rb][rr] + partial[3][rb][rr])) + partial[4][rb][rr];
            }
            float gx = gpre.x + g4[0], gy = gpre.y + g4[1];
            float gz = gpre.z + g4[2], gw = gpre.w + g4[3];
            float i_ = sigf(gx), f_ = sigf(gy), gg = tanhf(gz), o_ = sigf(gw);
            float cn = f_ * cr + i_ * gg;
            float hn = o_ * tanhf(cn);
            cr = m_ * cn + (1.f - m_) * cr;
            hr = m_ * hn + (1.f - m_) * hr;
            hbuf[cur ^ 1][rb][k0 + rkl] = hr;
            __hip_atomic_store(&hx[((((size_t)d * 32 + pair) * 2 + slot) * 2 + rb) * Hn + k0 + rkl],
                               hr, __ATOMIC_RELAXED, __HIP_MEMORY_SCOPE_AGENT);
            Hcat[((size_t)rbb * Tn + tg) * (2 * Hn) + d * Hn + k0 + rkl] = hr;
        }
        __syncthreads();   // barrier implies vmcnt(0): hx stores device-visible before flag
        if (tid == 0) {
            __hip_atomic_store(&flg[((d * 32 + pair) * 4 + ksp) * 16], stamp,
                               __ATOMIC_RELEASE, __HIP_MEMORY_SCOPE_AGENT);
        }
        if (tid < 300) {
            int sib = (ksp + 1 + tid / 100) & 3;
            int idx = tid % 100;
            int b = idx & 1, kk = idx >> 1;
            int* f = &flg[((d * 32 + pair) * 4 + sib) * 16];
            int spins = 0;
            while (__hip_atomic_load(f, __ATOMIC_ACQUIRE, __HIP_MEMORY_SCOPE_AGENT) < stamp &&
                   ++spins < (1 << 22)) {}
            float v = __hip_atomic_load(&hx[((((size_t)d * 32 + pair) * 2 + slot) * 2 + b) * Hn + sib * KS + kk],
                                        __ATOMIC_RELAXED, __HIP_MEMORY_SCOPE_AGENT);
            hbuf[cur ^ 1][b][sib * KS + kk] = v;
        }
        __syncthreads();
        cur ^= 1;
    }
    if (red_act) {
        hst[((size_t)d * Bn + rbb) * Hn + k0 + rkl] = hr;
        cst[((size_t)d * Bn + rbb) * Hn + k0 + rkl] = cr;
    }
}

// ---------------- emissions: E = (Hcat @ Wl^T + bl) * mask ----------------
// grid: 256 WGs x 128 rows each
__global__ __launch_bounds__(256) void emis_kernel(const float* __restrict__ mask,
                                                   const float* __restrict__ Wl,
                                                   const float* __restrict__ bl,
                                                   float* __restrict__ ws) {
    const float* Hcat = ws + OFF_HCAT;
    float* E = ws + OFF_E;
    __shared__ float Wls[Ln * 404];
    __shared__ float Hs[16 * 404];
    int tid = threadIdx.x;
    for (int i = tid; i < Ln * 100; i += 256) {
        int l = i / 100, k4 = i % 100;
        *(float4*)&Wls[l*404 + k4*4] = *(const float4*)(Wl + (size_t)l*Dn + k4*4);
    }
    int rbase = blockIdx.x * 128;
    for (int sub = 0; sub < 8; ++sub) {
        int r0 = rbase + sub * 16;
        __syncthreads();
        for (int i = tid; i < 16 * 100; i += 256) {
            int r = i / 100, k4 = i % 100;
            *(float4*)&Hs[r*404 + k4*4] = *(const float4*)(Hcat + (size_t)(r0 + r)*Dn + k4*4);
        }
        __syncthreads();
        for (int o = tid; o < 16 * Ln; o += 256) {
            int r = o / Ln, l = o % Ln;
            float acc = 0.f;
            #pragma unroll 4
            for (int k4 = 0; k4 < 100; ++k4) {
                float4 h = *(const float4*)&Hs[r*404 + k4*4];
                float4 wv = *(const float4*)&Wls[l*404 + k4*4];
                acc += h.x*wv.x + h.y*wv.y + h.z*wv.z + h.w*wv.w;
            }
            int row = r0 + r;            // row == b*T + t
            float m = mask[row];
            E[(size_t)row * Ln + l] = (acc + bl[l]) * m;
        }
    }
}

// ---------------- CRF forward (logZ) + numerator ----------------
__global__ __launch_bounds__(64) void crf_kernel(const float* __restrict__ mask,
                                                 const int* __restrict__ labels,
                                                 const float* __restrict__ trans,
                                                 const float* __restrict__ start,
                                                 const float* __restrict__ endv,
                                                 float* __restrict__ ws) {
    int b = blockIdx.x;
    int l = threadIdx.x;
    const float* E = ws + OFF_E;
    float* part = ws + OFF_PART;
    __shared__ float tr[Ln * Ln];
    __shared__ float al[Ln];
    for (int i = l; i < Ln * Ln; i += 64) tr[i] = trans[i];
    float alpha = -1e30f;
    if (l < Ln) { alpha = start[l] + E[((size_t)b * Tn) * Ln + l]; al[l] = alpha; }
    __syncthreads();
    for (int t = 1; t < Tn; ++t) {
        float mt = mask[(size_t)b * Tn + t];
        if (mt > 0.f) {               // wave-uniform branch
            float nv = alpha;
            if (l < Ln) {
                float v[Ln]; float mx = -1e30f;
                #pragma unroll
                for (int j = 0; j < Ln; ++j) { v[j] = al[j] + tr[j*Ln + l]; mx = fmaxf(mx, v[j]); }
                float s = 0.f;
                #pragma unroll
                for (int j = 0; j < Ln; ++j) s += __expf(v[j] - mx);
                nv = mx + __logf(s) + E[((size_t)b * Tn + t) * Ln + l];
            }
            __syncthreads();
            if (l < Ln) { al[l] = nv; alpha = nv; }
            __syncthreads();
        }
    }
    float v = (l < Ln) ? alpha + endv[l] : -1e30f;
    float mx = v;
    for (int off = 32; off; off >>= 1) mx = fmaxf(mx, __shfl_xor(mx, off));
    float s = (l < Ln) ? __expf(v - mx) : 0.f;
    for (int off = 32; off; off >>= 1) s += __shfl_xor(s, off);
    float logZ = mx + __logf(s);
    // numerator (parallel over t, wave reduce)
    float psum = 0.f, plen = 0.f;
    for (int t = l; t < Tn; t += 64) {
        float mt = mask[(size_t)b * Tn + t];
        plen += mt;
        if (t >= 1 && mt > 0.f) {
            int lt = labels[(size_t)b * Tn + t];
            int lp = labels[(size_t)b * Tn + t - 1];
            psum += E[((size_t)b * Tn + t) * Ln + lt] + tr[lp * Ln + lt];
        }
    }
    for (int off = 32; off; off >>= 1) { psum += __shfl_xor(psum, off); plen += __shfl_xor(plen, off); }
    if (l == 0) {
        int last = (int)(plen + 0.5f) - 1;
        int l0 = labels[(size_t)b * Tn];
        int yl = labels[(size_t)b * Tn + last];
        float num = start[l0] + E[((size_t)b * Tn) * Ln + l0] + psum + endv[yl];
        part[b] = num - logZ;
    }
}

// ---------------- Viterbi ----------------
__global__ __launch_bounds__(64) void vit_kernel(const float* __restrict__ mask,
                                                 const float* __restrict__ trans,
                                                 const float* __restrict__ start,
                                                 const float* __restrict__ endv,
                                                 float* __restrict__ ws,
                                                 float* __restrict__ out) {
    int b = blockIdx.x;
    int l = threadIdx.x;
    const float* E = ws + OFF_E;
    __shared__ float tr[Ln * Ln];
    __shared__ float dl[Ln];
    __shared__ unsigned char ptrs[Tn][Ln];
    __shared__ unsigned char ys[Tn];
    for (int i = l; i < Ln * Ln; i += 64) tr[i] = trans[i];
    float delta = -1e30f;
    if (l < Ln) { delta = start[l] + E[((size_t)b * Tn) * Ln + l]; dl[l] = delta; }
    __syncthreads();
    for (int t = 1; t < Tn; ++t) {
        float mt = mask[(size_t)b * Tn + t];
        float nd = delta; int np = (l < Ln) ? l : 0;
        if (l < Ln && mt > 0.f) {
            float best = -1e30f; int ba = 0;
            #pragma unroll
            for (int j = 0; j < Ln; ++j) {
                float c = dl[j] + tr[j * Ln + l];
                if (c > best) { best = c; ba = j; }  // strict > keeps first index (jnp.argmax)
            }
            nd = best + E[((size_t)b * Tn + t) * Ln + l];
            np = ba;
        }
        __syncthreads();
        if (l < Ln) { dl[l] = nd; ptrs[t][l] = (unsigned char)np; delta = nd; }
        __syncthreads();
    }
    if (l == 0) {
        float best = -1e30f; int y = 0;
        for (int j = 0; j < Ln; ++j) { float c = dl[j] + endv[j]; if (c > best) { best = c; y = j; } }
        ys[Tn - 1] = (unsigned char)y;
        for (int t = Tn - 1; t >= 1; --t) { y = ptrs[t][y]; ys[t - 1] = (unsigned char)y; }
    }
    __syncthreads();
    for (int t = l; t < Tn; t += 64) {
        float mt = mask[(size_t)b * Tn + t];
        out[1 + (size_t)b * Tn + t] = (mt > 0.f) ? (float)ys[t] : 0.f;
    }
}

// ---------------- finalize loss ----------------
__global__ __launch_bounds__(64) void fin_kernel(float* __restrict__ ws, float* __restrict__ out) {
    const float* part = ws + OFF_PART;
    int l = threadIdx.x;
    float v = (l < Bn) ? part[l] : 0.f;
    for (int off = 32; off; off >>= 1) v += __shfl_xor(v, off);
    if (l == 0) out[0] = -v / (float)Bn;
}

extern "C" void kernel_launch(void* const* d_in, const int* in_sizes, int n_in,
                              void* d_out, int out_size, void* d_ws, size_t ws_size,
                              hipStream_t stream) {
    (void)in_sizes; (void)n_in; (void)out_size; (void)ws_size;
    const float* X      = (const float*)d_in[0];
    const float* mask   = (const float*)d_in[1];
    const int*   labels = (const int*)d_in[2];
    const float* Wih_f  = (const float*)d_in[3];
    const float* Whh_f  = (const float*)d_in[4];
    const float* bih_f  = (const float*)d_in[5];
    const float* bhh_f  = (const float*)d_in[6];
    const float* Wih_b  = (const float*)d_in[7];
    const float* Whh_b  = (const float*)d_in[8];
    const float* bih_b  = (const float*)d_in[9];
    const float* bhh_b  = (const float*)d_in[10];
    const float* Wl     = (const float*)d_in[11];
    const float* bl     = (const float*)d_in[12];
    const float* trans  = (const float*)d_in[13];
    const float* start  = (const float*)d_in[14];
    const float* endv   = (const float*)d_in[15];
    float* ws  = (float*)d_ws;
    float* out = (float*)d_out;

    prep_kernel<<<128, 256, 0, stream>>>(Wih_f, bih_f, bhh_f,
                                         Wih_b, bih_b, bhh_b, ws);
    for (int c = 0; c < NCH; ++c) {
        gemm_kernel<<<dim3(13, 32, 2), 256, 0, stream>>>(X, ws, c);
        rec_kernel<<<dim3(KSPLIT, 32, 2), 1024, 0, stream>>>(mask, Whh_f, Whh_b, ws, c);
    }
    emis_kernel<<<256, 256, 0, stream>>>(mask, Wl, bl, ws);
    crf_kernel<<<64, 64, 0, stream>>>(mask, labels, trans, start, endv, ws);
    vit_kernel<<<64, 64, 0, stream>>>(mask, trans, start, endv, ws, out);
    fin_kernel<<<1, 64, 0, stream>>>(ws, out);
}

// Round 4
// 3991.090 us; speedup vs baseline: 3.0539x; 3.0539x over previous
//
#include <hip/hip_runtime.h>
#include <cmath>

#define Bn 64
#define Tn 512
#define Dn 400
#define Ln 25
#define Hn 200
#define G4n 800
#define TCn 64
#define NCH 8
#define NPADn 832
#define JV 24   // j per part-slice resident in VGPRs
#define JL 8    // j per part-slice resident in LDS
#define JS 8    // j per part-slice streamed from L2 each step  (JV+JL+JS = 40)

// ---- workspace layout (float offsets); total ~86 MB ----
constexpr size_t OFF_WIHT = 0;                                  // [2][400][832]
constexpr size_t OFF_WHHP = OFF_WIHT + (size_t)2*Dn*NPADn;      // [2][200(j)][200(k)][4(q)]
constexpr size_t OFF_BSUM = OFF_WHHP + (size_t)2*Hn*Hn*4;       // [2][800]
constexpr size_t OFF_G    = OFF_BSUM + (size_t)2*G4n;           // [2][64][64][800]
constexpr size_t OFF_HCAT = OFF_G + (size_t)2*Bn*TCn*G4n;       // [64][512][400]
constexpr size_t OFF_E    = OFF_HCAT + (size_t)Bn*Tn*2*Hn;      // [64][512][25]
constexpr size_t OFF_HST  = OFF_E + (size_t)Bn*Tn*Ln;           // [2][64][200]
constexpr size_t OFF_CST  = OFF_HST + (size_t)2*Bn*Hn;          // [2][64][200]
constexpr size_t OFF_PART = OFF_CST + (size_t)2*Bn*Hn;          // [64]

__device__ __forceinline__ float sigf(float x) { return 1.0f / (1.0f + expf(-x)); }

// ---------------- prep: transpose/pack weights, zero state ----------------
__global__ void prep_kernel(const float* __restrict__ Wih_f, const float* __restrict__ Whh_f,
                            const float* __restrict__ bih_f, const float* __restrict__ bhh_f,
                            const float* __restrict__ Wih_b, const float* __restrict__ Whh_b,
                            const float* __restrict__ bih_b, const float* __restrict__ bhh_b,
                            float* __restrict__ ws) {
    int tid = blockIdx.x * blockDim.x + threadIdx.x;
    int nth = gridDim.x * blockDim.x;
    float* WihT = ws + OFF_WIHT;
    float* WhhP = ws + OFF_WHHP;
    float* bsum = ws + OFF_BSUM;
    float* hst  = ws + OFF_HST;
    float* cst  = ws + OFF_CST;
    for (int i = tid; i < 2*Dn*NPADn; i += nth) {
        int d = i / (Dn*NPADn); int r = i % (Dn*NPADn); int k = r / NPADn; int g = r % NPADn;
        const float* W = d ? Wih_b : Wih_f;
        WihT[i] = (g < G4n) ? W[(size_t)g*Dn + k] : 0.0f;
    }
    for (int i = tid; i < 2*Hn*G4n; i += nth) {   // WhhP[d][j][k*4+q] = Whh[q*H+k][j]
        int d = i / (Hn*G4n); int r = i % (Hn*G4n);
        int j = r / G4n; int g = r % G4n;
        int k = g >> 2, q = g & 3;
        const float* W = d ? Whh_b : Whh_f;
        WhhP[i] = W[(size_t)(q*Hn + k)*Hn + j];
    }
    for (int i = tid; i < 2*G4n; i += nth) {
        int d = i / G4n; int g = i % G4n;
        bsum[i] = d ? (bih_b[g] + bhh_b[g]) : (bih_f[g] + bhh_f[g]);
    }
    for (int i = tid; i < 2*Bn*Hn; i += nth) { hst[i] = 0.0f; cst[i] = 0.0f; }
}

// ---------------- input projection GEMM for one time-chunk (both dirs) ----------------
// grid: (13 N-tiles, 32 b-pairs, 2 dir), 256 threads; BM=128 (2 b x 64 t), BN=64, BK=16
__global__ __launch_bounds__(256) void gemm_kernel(const float* __restrict__ X,
                                                   float* __restrict__ ws, int chunk) {
    const float* WihT = ws + OFF_WIHT;
    const float* bsum = ws + OFF_BSUM;
    float* G = ws + OFF_G;
    int d = blockIdx.z;
    int bp = blockIdx.y;          // batch pair
    int g0 = blockIdx.x * 64;
    int tid = threadIdx.x;
    int tx = tid % 16, ty = tid / 16;
    int t_base = (d == 0) ? chunk * TCn : (Tn - (chunk + 1) * TCn);
    const float* Bmat = WihT + (size_t)d * Dn * NPADn;

    __shared__ float As[16][136];
    __shared__ float Bs[16][68];
    float acc[8][4] = {{0.f}};
    int lr = tid / 2, lk = tid % 2;   // A load: row in [0,128), k-octet
    int bk = tid / 16, bg = tid % 16; // B load: k row, g-quad
    int a_b = bp * 2 + lr / 64;
    int a_t = t_base + (lr % 64);
    const float* Arow = X + ((size_t)a_b * Tn + a_t) * Dn;

    for (int kt = 0; kt < Dn; kt += 16) {
        float4 a4a = *(const float4*)(Arow + kt + lk * 8);
        float4 a4b = *(const float4*)(Arow + kt + lk * 8 + 4);
        float4 b4  = *(const float4*)(Bmat + (size_t)(kt + bk) * NPADn + g0 + bg * 4);
        __syncthreads();
        As[lk*8+0][lr] = a4a.x; As[lk*8+1][lr] = a4a.y;
        As[lk*8+2][lr] = a4a.z; As[lk*8+3][lr] = a4a.w;
        As[lk*8+4][lr] = a4b.x; As[lk*8+5][lr] = a4b.y;
        As[lk*8+6][lr] = a4b.z; As[lk*8+7][lr] = a4b.w;
        *(float4*)&Bs[bk][bg*4] = b4;
        __syncthreads();
        #pragma unroll
        for (int kk = 0; kk < 16; ++kk) {
            float4 af0 = *(const float4*)&As[kk][ty*8];
            float4 af1 = *(const float4*)&As[kk][ty*8+4];
            float4 bf  = *(const float4*)&Bs[kk][tx*4];
            acc[0][0] += af0.x*bf.x; acc[0][1] += af0.x*bf.y; acc[0][2] += af0.x*bf.z; acc[0][3] += af0.x*bf.w;
            acc[1][0] += af0.y*bf.x; acc[1][1] += af0.y*bf.y; acc[1][2] += af0.y*bf.z; acc[1][3] += af0.y*bf.w;
            acc[2][0] += af0.z*bf.x; acc[2][1] += af0.z*bf.y; acc[2][2] += af0.z*bf.z; acc[2][3] += af0.z*bf.w;
            acc[3][0] += af0.w*bf.x; acc[3][1] += af0.w*bf.y; acc[3][2] += af0.w*bf.z; acc[3][3] += af0.w*bf.w;
            acc[4][0] += af1.x*bf.x; acc[4][1] += af1.x*bf.y; acc[4][2] += af1.x*bf.z; acc[4][3] += af1.x*bf.w;
            acc[5][0] += af1.y*bf.x; acc[5][1] += af1.y*bf.y; acc[5][2] += af1.y*bf.z; acc[5][3] += af1.y*bf.w;
            acc[6][0] += af1.z*bf.x; acc[6][1] += af1.z*bf.y; acc[6][2] += af1.z*bf.z; acc[6][3] += af1.z*bf.w;
            acc[7][0] += af1.w*bf.x; acc[7][1] += af1.w*bf.y; acc[7][2] += af1.w*bf.z; acc[7][3] += af1.w*bf.w;
        }
    }
    #pragma unroll
    for (int ii = 0; ii < 8; ++ii) {
        int r = ty * 8 + ii;
        int b = bp * 2 + r / 64;
        int tloc = r % 64;
        #pragma unroll
        for (int jj = 0; jj < 4; ++jj) {
            int g = g0 + tx * 4 + jj;
            if (g < G4n) {
                int k = g % Hn, q = g / Hn;
                G[(((size_t)d*Bn + b)*TCn + tloc)*G4n + k*4 + q] = acc[ii][jj] + bsum[d*G4n + g];
            }
        }
    }
}

// ---------------- LSTM recurrence: weights resident in VGPR+LDS, one WG per (d,b) ----------------
// grid: (64 b, 2 dir) = 128 WGs, 1024 threads = 16 waves.
// thread (k = tid%200, part = tid/200 in [0,5)): gate-quad k over j-slice [part*40, part*40+40):
//   j offsets [0,24) in VGPRs, [24,32) in LDS, [32,40) streamed from L2 each step.
// part 0 doubles as reducer: sums partials, applies activations, updates h,c.
__global__ __launch_bounds__(1024, 4) void rec_kernel(const float* __restrict__ mask,
                                                      float* __restrict__ ws, int chunk) {
    const float* G = ws + OFF_G;
    float* Hcat = ws + OFF_HCAT;
    float* hst = ws + OFF_HST;
    float* cst = ws + OFF_CST;
    const float* WP = ws + OFF_WHHP;

    int b = blockIdx.x;
    int d = blockIdx.y;
    int tid = threadIdx.x;
    int k = tid % 200;
    int part = tid / 200;          // 0..5 (part 5: 24 idle threads)
    bool act = (part < 5);
    bool red = (tid < 200);

    __shared__ float4 wlds[5][JL][200];   // 125 KiB
    __shared__ float4 partial[4][200];    // 12.5 KiB (parts 1..4)
    __shared__ float  hbuf[2][208];       // 1.6 KiB

    const float* Wd = WP + (size_t)d * Hn * G4n;
    int base = part * 40;
    float4 wreg[JV];
    if (act) {
        #pragma unroll
        for (int jj = 0; jj < JV; ++jj)
            wreg[jj] = *(const float4*)(Wd + (size_t)(base + jj) * G4n + k * 4);
        #pragma unroll
        for (int jj = 0; jj < JL; ++jj)
            wlds[part][jj][k] = *(const float4*)(Wd + (size_t)(base + JV + jj) * G4n + k * 4);
    }
    float hr = 0.f, cr = 0.f;
    if (red) {
        hr = hst[((size_t)d * Bn + b) * Hn + k];
        cr = cst[((size_t)d * Bn + b) * Hn + k];
        hbuf[0][k] = hr;
    }
    __syncthreads();

    const float* Wst = Wd + (size_t)(base + JV + JL) * G4n + k * 4;
    const float* Grow = G + ((size_t)d * Bn + b) * TCn * G4n;
    const float* mrow = mask + (size_t)b * Tn;
    float* Hrow = Hcat + (size_t)b * Tn * (2 * Hn) + d * Hn;

    int cur = 0;
    for (int s = 0; s < TCn; ++s) {
        int tg, tloc;
        if (d == 0) { tloc = s; tg = chunk * TCn + s; }
        else        { tloc = TCn - 1 - s; tg = Tn - 1 - (chunk * TCn + s); }
        float4 acc = {0.f, 0.f, 0.f, 0.f};
        if (act) {
            // VGPR-resident j: 6 h-quads
            #pragma unroll
            for (int h4 = 0; h4 < 6; ++h4) {
                float4 hv = *(const float4*)&hbuf[cur][base + h4 * 4];
                acc.x += wreg[h4*4+0].x*hv.x; acc.y += wreg[h4*4+0].y*hv.x; acc.z += wreg[h4*4+0].z*hv.x; acc.w += wreg[h4*4+0].w*hv.x;
                acc.x += wreg[h4*4+1].x*hv.y; acc.y += wreg[h4*4+1].y*hv.y; acc.z += wreg[h4*4+1].z*hv.y; acc.w += wreg[h4*4+1].w*hv.y;
                acc.x += wreg[h4*4+2].x*hv.z; acc.y += wreg[h4*4+2].y*hv.z; acc.z += wreg[h4*4+2].z*hv.z; acc.w += wreg[h4*4+2].w*hv.z;
                acc.x += wreg[h4*4+3].x*hv.w; acc.y += wreg[h4*4+3].y*hv.w; acc.z += wreg[h4*4+3].z*hv.w; acc.w += wreg[h4*4+3].w*hv.w;
            }
            // LDS-resident j: 2 h-quads
            #pragma unroll
            for (int h4 = 0; h4 < 2; ++h4) {
                float4 hv = *(const float4*)&hbuf[cur][base + JV + h4 * 4];
                float4 w0 = wlds[part][h4*4+0][k];
                float4 w1 = wlds[part][h4*4+1][k];
                float4 w2 = wlds[part][h4*4+2][k];
                float4 w3 = wlds[part][h4*4+3][k];
                acc.x += w0.x*hv.x; acc.y += w0.y*hv.x; acc.z += w0.z*hv.x; acc.w += w0.w*hv.x;
                acc.x += w1.x*hv.y; acc.y += w1.y*hv.y; acc.z += w1.z*hv.y; acc.w += w1.w*hv.y;
                acc.x += w2.x*hv.z; acc.y += w2.y*hv.z; acc.z += w2.z*hv.z; acc.w += w2.w*hv.z;
                acc.x += w3.x*hv.w; acc.y += w3.y*hv.w; acc.z += w3.z*hv.w; acc.w += w3.w*hv.w;
            }
            // L2-streamed j: 2 h-quads
            #pragma unroll
            for (int h4 = 0; h4 < 2; ++h4) {
                float4 hv = *(const float4*)&hbuf[cur][base + JV + JL + h4 * 4];
                float4 w0 = *(const float4*)(Wst + (size_t)(h4*4+0) * G4n);
                float4 w1 = *(const float4*)(Wst + (size_t)(h4*4+1) * G4n);
                float4 w2 = *(const float4*)(Wst + (size_t)(h4*4+2) * G4n);
                float4 w3 = *(const float4*)(Wst + (size_t)(h4*4+3) * G4n);
                acc.x += w0.x*hv.x; acc.y += w0.y*hv.x; acc.z += w0.z*hv.x; acc.w += w0.w*hv.x;
                acc.x += w1.x*hv.y; acc.y += w1.y*hv.y; acc.z += w1.z*hv.y; acc.w += w1.w*hv.y;
                acc.x += w2.x*hv.z; acc.y += w2.y*hv.z; acc.z += w2.z*hv.z; acc.w += w2.w*hv.z;
                acc.x += w3.x*hv.w; acc.y += w3.y*hv.w; acc.z += w3.z*hv.w; acc.w += w3.w*hv.w;
            }
            if (part != 0) partial[part - 1][k] = acc;
        }
        __syncthreads();
        if (red) {
            float m_ = mrow[tg];
            float4 gpre = *(const float4*)(Grow + (size_t)tloc * G4n + k * 4);
            float4 p0 = partial[0][k];
            float4 p1 = partial[1][k];
            float4 p2 = partial[2][k];
            float4 p3 = partial[3][k];
            float gx = gpre.x + acc.x + ((p0.x + p1.x) + (p2.x + p3.x));
            float gy = gpre.y + acc.y + ((p0.y + p1.y) + (p2.y + p3.y));
            float gz = gpre.z + acc.z + ((p0.z + p1.z) + (p2.z + p3.z));
            float gw = gpre.w + acc.w + ((p0.w + p1.w) + (p2.w + p3.w));
            float i_ = sigf(gx), f_ = sigf(gy), gg = tanhf(gz), o_ = sigf(gw);
            float cn = f_ * cr + i_ * gg;
            float hn = o_ * tanhf(cn);
            cr = m_ * cn + (1.f - m_) * cr;
            hr = m_ * hn + (1.f - m_) * hr;
            hbuf[cur ^ 1][k] = hr;
            Hrow[(size_t)tg * (2 * Hn) + k] = hr;
        }
        __syncthreads();
        cur ^= 1;
    }
    if (red) {
        hst[((size_t)d * Bn + b) * Hn + k] = hr;
        cst[((size_t)d * Bn + b) * Hn + k] = cr;
    }
}

// ---------------- emissions: E = (Hcat @ Wl^T + bl) * mask ----------------
// grid: 256 WGs x 128 rows each
__global__ __launch_bounds__(256) void emis_kernel(const float* __restrict__ mask,
                                                   const float* __restrict__ Wl,
                                                   const float* __restrict__ bl,
                                                   float* __restrict__ ws) {
    const float* Hcat = ws + OFF_HCAT;
    float* E = ws + OFF_E;
    __shared__ float Wls[Ln * 404];
    __shared__ float Hs[16 * 404];
    int tid = threadIdx.x;
    for (int i = tid; i < Ln * 100; i += 256) {
        int l = i / 100, k4 = i % 100;
        *(float4*)&Wls[l*404 + k4*4] = *(const float4*)(Wl + (size_t)l*Dn + k4*4);
    }
    int rbase = blockIdx.x * 128;
    for (int sub = 0; sub < 8; ++sub) {
        int r0 = rbase + sub * 16;
        __syncthreads();
        for (int i = tid; i < 16 * 100; i += 256) {
            int r = i / 100, k4 = i % 100;
            *(float4*)&Hs[r*404 + k4*4] = *(const float4*)(Hcat + (size_t)(r0 + r)*Dn + k4*4);
        }
        __syncthreads();
        for (int o = tid; o < 16 * Ln; o += 256) {
            int r = o / Ln, l = o % Ln;
            float acc = 0.f;
            #pragma unroll 4
            for (int k4 = 0; k4 < 100; ++k4) {
                float4 h = *(const float4*)&Hs[r*404 + k4*4];
                float4 wv = *(const float4*)&Wls[l*404 + k4*4];
                acc += h.x*wv.x + h.y*wv.y + h.z*wv.z + h.w*wv.w;
            }
            int row = r0 + r;            // row == b*T + t
            float m = mask[row];
            E[(size_t)row * Ln + l] = (acc + bl[l]) * m;
        }
    }
}

// ---------------- CRF forward (logZ) + numerator ----------------
__global__ __launch_bounds__(64) void crf_kernel(const float* __restrict__ mask,
                                                 const int* __restrict__ labels,
                                                 const float* __restrict__ trans,
                                                 const float* __restrict__ start,
                                                 const float* __restrict__ endv,
                                                 float* __restrict__ ws) {
    int b = blockIdx.x;
    int l = threadIdx.x;
    const float* E = ws + OFF_E;
    float* part = ws + OFF_PART;
    __shared__ float tr[Ln * Ln];
    __shared__ float al[Ln];
    for (int i = l; i < Ln * Ln; i += 64) tr[i] = trans[i];
    float alpha = -1e30f;
    if (l < Ln) { alpha = start[l] + E[((size_t)b * Tn) * Ln + l]; al[l] = alpha; }
    __syncthreads();
    for (int t = 1; t < Tn; ++t) {
        float mt = mask[(size_t)b * Tn + t];
        if (mt > 0.f) {               // wave-uniform branch
            float nv = alpha;
            if (l < Ln) {
                float v[Ln]; float mx = -1e30f;
                #pragma unroll
                for (int j = 0; j < Ln; ++j) { v[j] = al[j] + tr[j*Ln + l]; mx = fmaxf(mx, v[j]); }
                float s = 0.f;
                #pragma unroll
                for (int j = 0; j < Ln; ++j) s += __expf(v[j] - mx);
                nv = mx + __logf(s) + E[((size_t)b * Tn + t) * Ln + l];
            }
            __syncthreads();
            if (l < Ln) { al[l] = nv; alpha = nv; }
            __syncthreads();
        }
    }
    float v = (l < Ln) ? alpha + endv[l] : -1e30f;
    float mx = v;
    for (int off = 32; off; off >>= 1) mx = fmaxf(mx, __shfl_xor(mx, off));
    float s = (l < Ln) ? __expf(v - mx) : 0.f;
    for (int off = 32; off; off >>= 1) s += __shfl_xor(s, off);
    float logZ = mx + __logf(s);
    // numerator (parallel over t, wave reduce)
    float psum = 0.f, plen = 0.f;
    for (int t = l; t < Tn; t += 64) {
        float mt = mask[(size_t)b * Tn + t];
        plen += mt;
        if (t >= 1 && mt > 0.f) {
            int lt = labels[(size_t)b * Tn + t];
            int lp = labels[(size_t)b * Tn + t - 1];
            psum += E[((size_t)b * Tn + t) * Ln + lt] + tr[lp * Ln + lt];
        }
    }
    for (int off = 32; off; off >>= 1) { psum += __shfl_xor(psum, off); plen += __shfl_xor(plen, off); }
    if (l == 0) {
        int last = (int)(plen + 0.5f) - 1;
        int l0 = labels[(size_t)b * Tn];
        int yl = labels[(size_t)b * Tn + last];
        float num = start[l0] + E[((size_t)b * Tn) * Ln + l0] + psum + endv[yl];
        part[b] = num - logZ;
    }
}

// ---------------- Viterbi ----------------
__global__ __launch_bounds__(64) void vit_kernel(const float* __restrict__ mask,
                                                 const float* __restrict__ trans,
                                                 const float* __restrict__ start,
                                                 const float* __restrict__ endv,
                                                 float* __restrict__ ws,
                                                 float* __restrict__ out) {
    int b = blockIdx.x;
    int l = threadIdx.x;
    const float* E = ws + OFF_E;
    __shared__ float tr[Ln * Ln];
    __shared__ float dl[Ln];
    __shared__ unsigned char ptrs[Tn][Ln];
    __shared__ unsigned char ys[Tn];
    for (int i = l; i < Ln * Ln; i += 64) tr[i] = trans[i];
    float delta = -1e30f;
    if (l < Ln) { delta = start[l] + E[((size_t)b * Tn) * Ln + l]; dl[l] = delta; }
    __syncthreads();
    for (int t = 1; t < Tn; ++t) {
        float mt = mask[(size_t)b * Tn + t];
        float nd = delta; int np = (l < Ln) ? l : 0;
        if (l < Ln && mt > 0.f) {
            float best = -1e30f; int ba = 0;
            #pragma unroll
            for (int j = 0; j < Ln; ++j) {
                float c = dl[j] + tr[j * Ln + l];
                if (c > best) { best = c; ba = j; }  // strict > keeps first index (jnp.argmax)
            }
            nd = best + E[((size_t)b * Tn + t) * Ln + l];
            np = ba;
        }
        __syncthreads();
        if (l < Ln) { dl[l] = nd; ptrs[t][l] = (unsigned char)np; delta = nd; }
        __syncthreads();
    }
    if (l == 0) {
        float best = -1e30f; int y = 0;
        for (int j = 0; j < Ln; ++j) { float c = dl[j] + endv[j]; if (c > best) { best = c; y = j; } }
        ys[Tn - 1] = (unsigned char)y;
        for (int t = Tn - 1; t >= 1; --t) { y = ptrs[t][y]; ys[t - 1] = (unsigned char)y; }
    }
    __syncthreads();
    for (int t = l; t < Tn; t += 64) {
        float mt = mask[(size_t)b * Tn + t];
        out[1 + (size_t)b * Tn + t] = (mt > 0.f) ? (float)ys[t] : 0.f;
    }
}

// ---------------- finalize loss ----------------
__global__ __launch_bounds__(64) void fin_kernel(float* __restrict__ ws, float* __restrict__ out) {
    const float* part = ws + OFF_PART;
    int l = threadIdx.x;
    float v = (l < Bn) ? part[l] : 0.f;
    for (int off = 32; off; off >>= 1) v += __shfl_xor(v, off);
    if (l == 0) out[0] = -v / (float)Bn;
}

extern "C" void kernel_launch(void* const* d_in, const int* in_sizes, int n_in,
                              void* d_out, int out_size, void* d_ws, size_t ws_size,
                              hipStream_t stream) {
    (void)in_sizes; (void)n_in; (void)out_size; (void)ws_size;
    const float* X      = (const float*)d_in[0];
    const float* mask   = (const float*)d_in[1];
    const int*   labels = (const int*)d_in[2];
    const float* Wih_f  = (const float*)d_in[3];
    const float* Whh_f  = (const float*)d_in[4];
    const float* bih_f  = (const float*)d_in[5];
    const float* bhh_f  = (const float*)d_in[6];
    const float* Wih_b  = (const float*)d_in[7];
    const float* Whh_b  = (const float*)d_in[8];
    const float* bih_b  = (const float*)d_in[9];
    const float* bhh_b  = (const float*)d_in[10];
    const float* Wl     = (const float*)d_in[11];
    const float* bl     = (const float*)d_in[12];
    const float* trans  = (const float*)d_in[13];
    const float* start  = (const float*)d_in[14];
    const float* endv   = (const float*)d_in[15];
    float* ws  = (float*)d_ws;
    float* out = (float*)d_out;

    prep_kernel<<<128, 256, 0, stream>>>(Wih_f, Whh_f, bih_f, bhh_f,
                                         Wih_b, Whh_b, bih_b, bhh_b, ws);
    for (int c = 0; c < NCH; ++c) {
        gemm_kernel<<<dim3(13, 32, 2), 256, 0, stream>>>(X, ws, c);
        rec_kernel<<<dim3(Bn, 2), 1024, 0, stream>>>(mask, ws, c);
    }
    emis_kernel<<<256, 256, 0, stream>>>(mask, Wl, bl, ws);
    crf_kernel<<<64, 64, 0, stream>>>(mask, labels, trans, start, endv, ws);
    vit_kernel<<<64, 64, 0, stream>>>(mask, trans, start, endv, ws, out);
    fin_kernel<<<1, 64, 0, stream>>>(ws, out);
}

// Round 5
// 3511.052 us; speedup vs baseline: 3.4714x; 1.1367x over previous
//
#include <hip/hip_runtime.h>
#include <cmath>

#define Bn 64
#define Tn 512
#define Dn 400
#define Ln 25
#define Hn 200
#define G4n 800
#define TCn 64
#define NCH 8
#define NPADn 832
#define JV 24   // j per part-slice resident in VGPRs
#define JL 8    // j per part-slice resident in LDS
#define JS 8    // j per part-slice streamed from L2 each step  (JV+JL+JS = 40)

// ---- workspace layout (float offsets); total ~86 MB ----
constexpr size_t OFF_WIHT = 0;                                  // [2][400][832]
constexpr size_t OFF_WHHP = OFF_WIHT + (size_t)2*Dn*NPADn;      // [2][200(j)][200(k)][4(q)]
constexpr size_t OFF_BSUM = OFF_WHHP + (size_t)2*Hn*Hn*4;       // [2][800]
constexpr size_t OFF_G    = OFF_BSUM + (size_t)2*G4n;           // [2][64][64][800]
constexpr size_t OFF_HCAT = OFF_G + (size_t)2*Bn*TCn*G4n;       // [64][512][400]
constexpr size_t OFF_E    = OFF_HCAT + (size_t)Bn*Tn*2*Hn;      // [64][512][25]
constexpr size_t OFF_HST  = OFF_E + (size_t)Bn*Tn*Ln;           // [2][64][200]
constexpr size_t OFF_CST  = OFF_HST + (size_t)2*Bn*Hn;          // [2][64][200]
constexpr size_t OFF_PART = OFF_CST + (size_t)2*Bn*Hn;          // [64]

__device__ __forceinline__ float sigf(float x) { return 1.0f / (1.0f + expf(-x)); }

// ---------------- prep: transpose/pack weights, zero state ----------------
__global__ void prep_kernel(const float* __restrict__ Wih_f, const float* __restrict__ Whh_f,
                            const float* __restrict__ bih_f, const float* __restrict__ bhh_f,
                            const float* __restrict__ Wih_b, const float* __restrict__ Whh_b,
                            const float* __restrict__ bih_b, const float* __restrict__ bhh_b,
                            float* __restrict__ ws) {
    int tid = blockIdx.x * blockDim.x + threadIdx.x;
    int nth = gridDim.x * blockDim.x;
    float* WihT = ws + OFF_WIHT;
    float* WhhP = ws + OFF_WHHP;
    float* bsum = ws + OFF_BSUM;
    float* hst  = ws + OFF_HST;
    float* cst  = ws + OFF_CST;
    for (int i = tid; i < 2*Dn*NPADn; i += nth) {
        int d = i / (Dn*NPADn); int r = i % (Dn*NPADn); int k = r / NPADn; int g = r % NPADn;
        const float* W = d ? Wih_b : Wih_f;
        WihT[i] = (g < G4n) ? W[(size_t)g*Dn + k] : 0.0f;
    }
    for (int i = tid; i < 2*Hn*G4n; i += nth) {   // WhhP[d][j][k*4+q] = Whh[q*H+k][j]
        int d = i / (Hn*G4n); int r = i % (Hn*G4n);
        int j = r / G4n; int g = r % G4n;
        int k = g >> 2, q = g & 3;
        const float* W = d ? Whh_b : Whh_f;
        WhhP[i] = W[(size_t)(q*Hn + k)*Hn + j];
    }
    for (int i = tid; i < 2*G4n; i += nth) {
        int d = i / G4n; int g = i % G4n;
        bsum[i] = d ? (bih_b[g] + bhh_b[g]) : (bih_f[g] + bhh_f[g]);
    }
    for (int i = tid; i < 2*Bn*Hn; i += nth) { hst[i] = 0.0f; cst[i] = 0.0f; }
}

// ---------------- input projection GEMM for one time-chunk (both dirs) ----------------
// grid: (13 N-tiles, 32 b-pairs, 2 dir), 256 threads; BM=128 (2 b x 64 t), BN=64, BK=16
__global__ __launch_bounds__(256) void gemm_kernel(const float* __restrict__ X,
                                                   float* __restrict__ ws, int chunk) {
    const float* WihT = ws + OFF_WIHT;
    const float* bsum = ws + OFF_BSUM;
    float* G = ws + OFF_G;
    int d = blockIdx.z;
    int bp = blockIdx.y;          // batch pair
    int g0 = blockIdx.x * 64;
    int tid = threadIdx.x;
    int tx = tid % 16, ty = tid / 16;
    int t_base = (d == 0) ? chunk * TCn : (Tn - (chunk + 1) * TCn);
    const float* Bmat = WihT + (size_t)d * Dn * NPADn;

    __shared__ float As[16][136];
    __shared__ float Bs[16][68];
    float acc[8][4] = {{0.f}};
    int lr = tid / 2, lk = tid % 2;   // A load: row in [0,128), k-octet
    int bk = tid / 16, bg = tid % 16; // B load: k row, g-quad
    int a_b = bp * 2 + lr / 64;
    int a_t = t_base + (lr % 64);
    const float* Arow = X + ((size_t)a_b * Tn + a_t) * Dn;

    for (int kt = 0; kt < Dn; kt += 16) {
        float4 a4a = *(const float4*)(Arow + kt + lk * 8);
        float4 a4b = *(const float4*)(Arow + kt + lk * 8 + 4);
        float4 b4  = *(const float4*)(Bmat + (size_t)(kt + bk) * NPADn + g0 + bg * 4);
        __syncthreads();
        As[lk*8+0][lr] = a4a.x; As[lk*8+1][lr] = a4a.y;
        As[lk*8+2][lr] = a4a.z; As[lk*8+3][lr] = a4a.w;
        As[lk*8+4][lr] = a4b.x; As[lk*8+5][lr] = a4b.y;
        As[lk*8+6][lr] = a4b.z; As[lk*8+7][lr] = a4b.w;
        *(float4*)&Bs[bk][bg*4] = b4;
        __syncthreads();
        #pragma unroll
        for (int kk = 0; kk < 16; ++kk) {
            float4 af0 = *(const float4*)&As[kk][ty*8];
            float4 af1 = *(const float4*)&As[kk][ty*8+4];
            float4 bf  = *(const float4*)&Bs[kk][tx*4];
            acc[0][0] += af0.x*bf.x; acc[0][1] += af0.x*bf.y; acc[0][2] += af0.x*bf.z; acc[0][3] += af0.x*bf.w;
            acc[1][0] += af0.y*bf.x; acc[1][1] += af0.y*bf.y; acc[1][2] += af0.y*bf.z; acc[1][3] += af0.y*bf.w;
            acc[2][0] += af0.z*bf.x; acc[2][1] += af0.z*bf.y; acc[2][2] += af0.z*bf.z; acc[2][3] += af0.z*bf.w;
            acc[3][0] += af0.w*bf.x; acc[3][1] += af0.w*bf.y; acc[3][2] += af0.w*bf.z; acc[3][3] += af0.w*bf.w;
            acc[4][0] += af1.x*bf.x; acc[4][1] += af1.x*bf.y; acc[4][2] += af1.x*bf.z; acc[4][3] += af1.x*bf.w;
            acc[5][0] += af1.y*bf.x; acc[5][1] += af1.y*bf.y; acc[5][2] += af1.y*bf.z; acc[5][3] += af1.y*bf.w;
            acc[6][0] += af1.z*bf.x; acc[6][1] += af1.z*bf.y; acc[6][2] += af1.z*bf.z; acc[6][3] += af1.z*bf.w;
            acc[7][0] += af1.w*bf.x; acc[7][1] += af1.w*bf.y; acc[7][2] += af1.w*bf.z; acc[7][3] += af1.w*bf.w;
        }
    }
    #pragma unroll
    for (int ii = 0; ii < 8; ++ii) {
        int r = ty * 8 + ii;
        int b = bp * 2 + r / 64;
        int tloc = r % 64;
        #pragma unroll
        for (int jj = 0; jj < 4; ++jj) {
            int g = g0 + tx * 4 + jj;
            if (g < G4n) {
                int k = g % Hn, q = g / Hn;
                G[(((size_t)d*Bn + b)*TCn + tloc)*G4n + k*4 + q] = acc[ii][jj] + bsum[d*G4n + g];
            }
        }
    }
}

// ---------------- LSTM recurrence: weights resident in VGPR+LDS, one WG per (d,b) ----------------
// grid: (64 b, 2 dir) = 128 WGs, 1024 threads = 16 waves.
// thread (k = tid%200, part = tid/200 in [0,5)): gate-quad k over j-slice [part*40, part*40+40):
//   j offsets [0,24) in VGPRs, [24,32) in LDS, [32,40) streamed from L2 each step.
// part 0 doubles as reducer. mask+G loads issued at loop TOP (prefetch across the gemv phase).
__global__ __launch_bounds__(1024, 4) void rec_kernel(const float* __restrict__ mask,
                                                      float* __restrict__ ws, int chunk) {
    const float* G = ws + OFF_G;
    float* Hcat = ws + OFF_HCAT;
    float* hst = ws + OFF_HST;
    float* cst = ws + OFF_CST;
    const float* WP = ws + OFF_WHHP;

    int b = blockIdx.x;
    int d = blockIdx.y;
    int tid = threadIdx.x;
    int k = tid % 200;
    int part = tid / 200;          // 0..5 (part 5: 24 idle threads)
    bool act = (part < 5);
    bool red = (tid < 200);

    __shared__ float4 wlds[5][JL][200];   // 125 KiB
    __shared__ float4 partial[4][200];    // 12.5 KiB (parts 1..4)
    __shared__ float  hbuf[2][208];       // 1.6 KiB

    const float* Wd = WP + (size_t)d * Hn * G4n;
    int base = part * 40;
    float4 wreg[JV];
    if (act) {
        #pragma unroll
        for (int jj = 0; jj < JV; ++jj)
            wreg[jj] = *(const float4*)(Wd + (size_t)(base + jj) * G4n + k * 4);
        #pragma unroll
        for (int jj = 0; jj < JL; ++jj)
            wlds[part][jj][k] = *(const float4*)(Wd + (size_t)(base + JV + jj) * G4n + k * 4);
    }
    float hr = 0.f, cr = 0.f;
    if (red) {
        hr = hst[((size_t)d * Bn + b) * Hn + k];
        cr = cst[((size_t)d * Bn + b) * Hn + k];
        hbuf[0][k] = hr;
    }
    __syncthreads();

    const float* Wst = Wd + (size_t)(base + JV + JL) * G4n + k * 4;
    const float* Grow = G + ((size_t)d * Bn + b) * TCn * G4n;
    const float* mrow = mask + (size_t)b * Tn;
    float* Hrow = Hcat + (size_t)b * Tn * (2 * Hn) + d * Hn;

    int cur = 0;
    for (int s = 0; s < TCn; ++s) {
        int tg, tloc;
        if (d == 0) { tloc = s; tg = chunk * TCn + s; }
        else        { tloc = TCn - 1 - s; tg = Tn - 1 - (chunk * TCn + s); }
        // ---- prefetch (issued before gemv; consumed after the barrier) ----
        float m_ = 0.f; float4 gpre = {0.f, 0.f, 0.f, 0.f};
        if (red) {
            m_ = mrow[tg];
            gpre = *(const float4*)(Grow + (size_t)tloc * G4n + k * 4);
        }
        float4 acc = {0.f, 0.f, 0.f, 0.f};
        if (act) {
            // VGPR-resident j: 6 h-quads
            #pragma unroll
            for (int h4 = 0; h4 < 6; ++h4) {
                float4 hv = *(const float4*)&hbuf[cur][base + h4 * 4];
                acc.x += wreg[h4*4+0].x*hv.x; acc.y += wreg[h4*4+0].y*hv.x; acc.z += wreg[h4*4+0].z*hv.x; acc.w += wreg[h4*4+0].w*hv.x;
                acc.x += wreg[h4*4+1].x*hv.y; acc.y += wreg[h4*4+1].y*hv.y; acc.z += wreg[h4*4+1].z*hv.y; acc.w += wreg[h4*4+1].w*hv.y;
                acc.x += wreg[h4*4+2].x*hv.z; acc.y += wreg[h4*4+2].y*hv.z; acc.z += wreg[h4*4+2].z*hv.z; acc.w += wreg[h4*4+2].w*hv.z;
                acc.x += wreg[h4*4+3].x*hv.w; acc.y += wreg[h4*4+3].y*hv.w; acc.z += wreg[h4*4+3].z*hv.w; acc.w += wreg[h4*4+3].w*hv.w;
            }
            // LDS-resident j: 2 h-quads
            #pragma unroll
            for (int h4 = 0; h4 < 2; ++h4) {
                float4 hv = *(const float4*)&hbuf[cur][base + JV + h4 * 4];
                float4 w0 = wlds[part][h4*4+0][k];
                float4 w1 = wlds[part][h4*4+1][k];
                float4 w2 = wlds[part][h4*4+2][k];
                float4 w3 = wlds[part][h4*4+3][k];
                acc.x += w0.x*hv.x; acc.y += w0.y*hv.x; acc.z += w0.z*hv.x; acc.w += w0.w*hv.x;
                acc.x += w1.x*hv.y; acc.y += w1.y*hv.y; acc.z += w1.z*hv.y; acc.w += w1.w*hv.y;
                acc.x += w2.x*hv.z; acc.y += w2.y*hv.z; acc.z += w2.z*hv.z; acc.w += w2.w*hv.z;
                acc.x += w3.x*hv.w; acc.y += w3.y*hv.w; acc.z += w3.z*hv.w; acc.w += w3.w*hv.w;
            }
            // L2-streamed j: 2 h-quads
            #pragma unroll
            for (int h4 = 0; h4 < 2; ++h4) {
                float4 hv = *(const float4*)&hbuf[cur][base + JV + JL + h4 * 4];
                float4 w0 = *(const float4*)(Wst + (size_t)(h4*4+0) * G4n);
                float4 w1 = *(const float4*)(Wst + (size_t)(h4*4+1) * G4n);
                float4 w2 = *(const float4*)(Wst + (size_t)(h4*4+2) * G4n);
                float4 w3 = *(const float4*)(Wst + (size_t)(h4*4+3) * G4n);
                acc.x += w0.x*hv.x; acc.y += w0.y*hv.x; acc.z += w0.z*hv.x; acc.w += w0.w*hv.x;
                acc.x += w1.x*hv.y; acc.y += w1.y*hv.y; acc.z += w1.z*hv.y; acc.w += w1.w*hv.y;
                acc.x += w2.x*hv.z; acc.y += w2.y*hv.z; acc.z += w2.z*hv.z; acc.w += w2.w*hv.z;
                acc.x += w3.x*hv.w; acc.y += w3.y*hv.w; acc.z += w3.z*hv.w; acc.w += w3.w*hv.w;
            }
            if (part != 0) partial[part - 1][k] = acc;
        }
        __syncthreads();
        if (red) {
            float4 p0 = partial[0][k];
            float4 p1 = partial[1][k];
            float4 p2 = partial[2][k];
            float4 p3 = partial[3][k];
            float gx = gpre.x + acc.x + ((p0.x + p1.x) + (p2.x + p3.x));
            float gy = gpre.y + acc.y + ((p0.y + p1.y) + (p2.y + p3.y));
            float gz = gpre.z + acc.z + ((p0.z + p1.z) + (p2.z + p3.z));
            float gw = gpre.w + acc.w + ((p0.w + p1.w) + (p2.w + p3.w));
            float i_ = sigf(gx), f_ = sigf(gy), gg = tanhf(gz), o_ = sigf(gw);
            float cn = f_ * cr + i_ * gg;
            float hn = o_ * tanhf(cn);
            cr = m_ * cn + (1.f - m_) * cr;
            hr = m_ * hn + (1.f - m_) * hr;
            hbuf[cur ^ 1][k] = hr;
            Hrow[(size_t)tg * (2 * Hn) + k] = hr;
        }
        __syncthreads();
        cur ^= 1;
    }
    if (red) {
        hst[((size_t)d * Bn + b) * Hn + k] = hr;
        cst[((size_t)d * Bn + b) * Hn + k] = cr;
    }
}

// ---------------- emissions: E = (Hcat @ Wl^T + bl) * mask ----------------
// grid: 256 WGs x 128 rows each
__global__ __launch_bounds__(256) void emis_kernel(const float* __restrict__ mask,
                                                   const float* __restrict__ Wl,
                                                   const float* __restrict__ bl,
                                                   float* __restrict__ ws) {
    const float* Hcat = ws + OFF_HCAT;
    float* E = ws + OFF_E;
    __shared__ float Wls[Ln * 404];
    __shared__ float Hs[16 * 404];
    int tid = threadIdx.x;
    for (int i = tid; i < Ln * 100; i += 256) {
        int l = i / 100, k4 = i % 100;
        *(float4*)&Wls[l*404 + k4*4] = *(const float4*)(Wl + (size_t)l*Dn + k4*4);
    }
    int rbase = blockIdx.x * 128;
    for (int sub = 0; sub < 8; ++sub) {
        int r0 = rbase + sub * 16;
        __syncthreads();
        for (int i = tid; i < 16 * 100; i += 256) {
            int r = i / 100, k4 = i % 100;
            *(float4*)&Hs[r*404 + k4*4] = *(const float4*)(Hcat + (size_t)(r0 + r)*Dn + k4*4);
        }
        __syncthreads();
        for (int o = tid; o < 16 * Ln; o += 256) {
            int r = o / Ln, l = o % Ln;
            float acc = 0.f;
            #pragma unroll 4
            for (int k4 = 0; k4 < 100; ++k4) {
                float4 h = *(const float4*)&Hs[r*404 + k4*4];
                float4 wv = *(const float4*)&Wls[l*404 + k4*4];
                acc += h.x*wv.x + h.y*wv.y + h.z*wv.z + h.w*wv.w;
            }
            int row = r0 + r;            // row == b*T + t
            float m = mask[row];
            E[(size_t)row * Ln + l] = (acc + bl[l]) * m;
        }
    }
}

// ---------------- fused CRF-forward + Viterbi: 128 one-wave blocks ----------------
// block 0..63: CRF logZ+numerator for batch b; block 64..127: Viterbi for b-64.
// E row staged in LDS; alpha/delta vector in LDS (read as 8x b128 broadcast);
// trans column in 25 regs/lane; no barriers in the scan (single wave => ordered LDS).
__global__ __launch_bounds__(64) void decode_kernel(const float* __restrict__ mask,
                                                    const int* __restrict__ labels,
                                                    const float* __restrict__ trans,
                                                    const float* __restrict__ start,
                                                    const float* __restrict__ endv,
                                                    float* __restrict__ ws,
                                                    float* __restrict__ out) {
    int role = blockIdx.x >> 6;
    int b = blockIdx.x & 63;
    int l = threadIdx.x;
    const float* E = ws + OFF_E;
    float* part = ws + OFF_PART;

    __shared__ __align__(16) float Es[Tn * Ln];     // 51200 B
    __shared__ __align__(16) float ms[Tn];          // 2048 B
    __shared__ float trs[Ln * Ln];                  // 2500 B
    __shared__ __align__(16) float als[32];
    __shared__ unsigned char ptrs[Tn][Ln];          // 12800 B (vit only)
    __shared__ unsigned char ys[Tn];                // 512 B  (vit only)

    {   // stage E row, mask row, trans (single wave: ordering via lgkmcnt)
        const float4* src = (const float4*)(E + (size_t)b * Tn * Ln);
        float4* dst = (float4*)Es;
        for (int i = l; i < Tn * Ln / 4; i += 64) dst[i] = src[i];
        const float4* msrc = (const float4*)(mask + (size_t)b * Tn);
        float4* mdst = (float4*)ms;
        for (int i = l; i < Tn / 4; i += 64) mdst[i] = msrc[i];
        for (int i = l; i < Ln * Ln; i += 64) trs[i] = trans[i];
    }
    // sequence length (mask is 1s then 0s)
    float cnt = 0.f;
    for (int t = l; t < Tn; t += 64) cnt += mask[(size_t)b * Tn + t];
    for (int off = 32; off; off >>= 1) cnt += __shfl_xor(cnt, off);
    int len = (int)(cnt + 0.5f);

    // per-lane trans column: trc[j] = trans[j][l]; pads -1e30
    float trc[32];
    #pragma unroll
    for (int j = 0; j < 32; ++j) trc[j] = -1e30f;
    if (l < Ln) {
        for (int j = 0; j < Ln; ++j) trc[j] = trans[j * Ln + l];
    }
    __syncthreads();

    if (role == 0) {
        // ---- CRF forward ----
        float alpha = -1e30f;
        if (l < Ln) alpha = start[l] + Es[l];
        if (l < 32) als[l] = (l < Ln) ? alpha : -1e30f;
        for (int t = 1; t < len; ++t) {
            float av[32];
            {
                const float4* ap = (const float4*)als;
                #pragma unroll
                for (int q = 0; q < 8; ++q) {
                    float4 a = ap[q];
                    av[q*4+0] = a.x; av[q*4+1] = a.y; av[q*4+2] = a.z; av[q*4+3] = a.w;
                }
            }
            float v[32];
            #pragma unroll
            for (int j = 0; j < 32; ++j) v[j] = av[j] + trc[j];
            float r[16];
            #pragma unroll
            for (int j = 0; j < 16; ++j) r[j] = fmaxf(v[j], v[j+16]);
            #pragma unroll
            for (int j = 0; j < 8; ++j) r[j] = fmaxf(r[j], r[j+8]);
            #pragma unroll
            for (int j = 0; j < 4; ++j) r[j] = fmaxf(r[j], r[j+4]);
            float mx = fmaxf(fmaxf(r[0], r[1]), fmaxf(r[2], r[3]));
            float e[32];
            #pragma unroll
            for (int j = 0; j < 32; ++j) e[j] = __expf(v[j] - mx);
            #pragma unroll
            for (int j = 0; j < 16; ++j) e[j] += e[j+16];
            #pragma unroll
            for (int j = 0; j < 8; ++j) e[j] += e[j+8];
            #pragma unroll
            for (int j = 0; j < 4; ++j) e[j] += e[j+4];
            float s = (e[0] + e[1]) + (e[2] + e[3]);
            float nv = mx + __logf(s) + Es[t * Ln + l];
            if (l < Ln) { als[l] = nv; alpha = nv; }
        }
        // logZ
        float vfin = (l < Ln) ? alpha + endv[l] : -1e30f;
        float mxf = vfin;
        for (int off = 32; off; off >>= 1) mxf = fmaxf(mxf, __shfl_xor(mxf, off));
        float sf = (l < Ln) ? __expf(vfin - mxf) : 0.f;
        for (int off = 32; off; off >>= 1) sf += __shfl_xor(sf, off);
        float logZ = mxf + __logf(sf);
        // numerator
        float psum = 0.f;
        for (int t = l; t < len; t += 64) {
            if (t >= 1) {
                int lt = labels[(size_t)b * Tn + t];
                int lp = labels[(size_t)b * Tn + t - 1];
                psum += Es[t * Ln + lt] + trs[lp * Ln + lt];
            }
        }
        for (int off = 32; off; off >>= 1) psum += __shfl_xor(psum, off);
        if (l == 0) {
            int l0 = labels[(size_t)b * Tn];
            int yl = labels[(size_t)b * Tn + len - 1];
            part[b] = start[l0] + Es[l0] + psum + endv[yl] - logZ;
        }
    } else {
        // ---- Viterbi ----
        float delta = (l < Ln) ? start[l] + Es[l] : -1e30f;
        if (l < 32) als[l] = (l < Ln) ? delta : -1e30f;
        for (int t = 1; t < len; ++t) {
            float av[32];
            {
                const float4* ap = (const float4*)als;
                #pragma unroll
                for (int q = 0; q < 8; ++q) {
                    float4 a = ap[q];
                    av[q*4+0] = a.x; av[q*4+1] = a.y; av[q*4+2] = a.z; av[q*4+3] = a.w;
                }
            }
            float best = -1e30f; int ba = 0;
            #pragma unroll
            for (int j = 0; j < Ln; ++j) {
                float c = av[j] + trc[j];
                if (c > best) { best = c; ba = j; }   // strict >: first-max (jnp.argmax)
            }
            float nd = best + Es[t * Ln + l];
            if (l < Ln) { als[l] = nd; ptrs[t][l] = (unsigned char)ba; delta = nd; }
        }
        (void)delta;
        // final argmax over delta + end (redundantly on all lanes; lane 0 uses it)
        float av[32];
        {
            const float4* ap = (const float4*)als;
            #pragma unroll
            for (int q = 0; q < 8; ++q) {
                float4 a = ap[q];
                av[q*4+0] = a.x; av[q*4+1] = a.y; av[q*4+2] = a.z; av[q*4+3] = a.w;
            }
        }
        float bb = -1e30f; int y = 0;
        for (int j = 0; j < Ln; ++j) {
            float c = av[j] + endv[j];
            if (c > bb) { bb = c; y = j; }
        }
        if (l == 0) {
            ys[len - 1] = (unsigned char)y;
            int yy = y;
            for (int t = len - 1; t >= 1; --t) { yy = ptrs[t][yy]; ys[t - 1] = (unsigned char)yy; }
        }
        for (int t = l; t < Tn; t += 64) {
            out[1 + (size_t)b * Tn + t] = (t < len) ? (float)ys[t] : 0.f;
        }
    }
}

// ---------------- finalize loss ----------------
__global__ __launch_bounds__(64) void fin_kernel(float* __restrict__ ws, float* __restrict__ out) {
    const float* part = ws + OFF_PART;
    int l = threadIdx.x;
    float v = (l < Bn) ? part[l] : 0.f;
    for (int off = 32; off; off >>= 1) v += __shfl_xor(v, off);
    if (l == 0) out[0] = -v / (float)Bn;
}

extern "C" void kernel_launch(void* const* d_in, const int* in_sizes, int n_in,
                              void* d_out, int out_size, void* d_ws, size_t ws_size,
                              hipStream_t stream) {
    (void)in_sizes; (void)n_in; (void)out_size; (void)ws_size;
    const float* X      = (const float*)d_in[0];
    const float* mask   = (const float*)d_in[1];
    const int*   labels = (const int*)d_in[2];
    const float* Wih_f  = (const float*)d_in[3];
    const float* Whh_f  = (const float*)d_in[4];
    const float* bih_f  = (const float*)d_in[5];
    const float* bhh_f  = (const float*)d_in[6];
    const float* Wih_b  = (const float*)d_in[7];
    const float* Whh_b  = (const float*)d_in[8];
    const float* bih_b  = (const float*)d_in[9];
    const float* bhh_b  = (const float*)d_in[10];
    const float* Wl     = (const float*)d_in[11];
    const float* bl     = (const float*)d_in[12];
    const float* trans  = (const float*)d_in[13];
    const float* start  = (const float*)d_in[14];
    const float* endv   = (const float*)d_in[15];
    float* ws  = (float*)d_ws;
    float* out = (float*)d_out;

    prep_kernel<<<128, 256, 0, stream>>>(Wih_f, Whh_f, bih_f, bhh_f,
                                         Wih_b, Whh_b, bih_b, bhh_b, ws);
    for (int c = 0; c < NCH; ++c) {
        gemm_kernel<<<dim3(13, 32, 2), 256, 0, stream>>>(X, ws, c);
        rec_kernel<<<dim3(Bn, 2), 1024, 0, stream>>>(mask, ws, c);
    }
    emis_kernel<<<256, 256, 0, stream>>>(mask, Wl, bl, ws);
    decode_kernel<<<128, 64, 0, stream>>>(mask, labels, trans, start, endv, ws, out);
    fin_kernel<<<1, 64, 0, stream>>>(ws, out);
}

// Round 6
// 3145.018 us; speedup vs baseline: 3.8755x; 1.1164x over previous
//
#include <hip/hip_runtime.h>
#include <cmath>

#define Bn 64
#define Tn 512
#define Dn 400
#define Ln 25
#define Hn 200
#define G4n 800
#define TCn 64
#define NCH 8
#define NPADn 832
#define JV 24   // j per part-slice resident in VGPRs/AGPRs
#define JL 8    // j per part-slice resident in LDS
#define JS 8    // j per part-slice streamed from L2 each step  (JV+JL+JS = 40)

// ---- workspace layout (float offsets); total ~86 MB ----
constexpr size_t OFF_WIHT = 0;                                  // [2][400][832]
constexpr size_t OFF_WHHP = OFF_WIHT + (size_t)2*Dn*NPADn;      // [2][200(j)][200(k)][4(q)]
constexpr size_t OFF_BSUM = OFF_WHHP + (size_t)2*Hn*Hn*4;       // [2][800]
constexpr size_t OFF_G    = OFF_BSUM + (size_t)2*G4n;           // [2][64][64][800]
constexpr size_t OFF_HCAT = OFF_G + (size_t)2*Bn*TCn*G4n;       // [64][512][400]
constexpr size_t OFF_E    = OFF_HCAT + (size_t)Bn*Tn*2*Hn;      // [64][512][25]
constexpr size_t OFF_HST  = OFF_E + (size_t)Bn*Tn*Ln;           // [2][64][200]
constexpr size_t OFF_CST  = OFF_HST + (size_t)2*Bn*Hn;          // [2][64][200]
constexpr size_t OFF_PART = OFF_CST + (size_t)2*Bn*Hn;          // [64]

__device__ __forceinline__ float sigf(float x) { return 1.0f / (1.0f + expf(-x)); }

// ---------------- prep: transpose/pack weights, zero state ----------------
__global__ void prep_kernel(const float* __restrict__ Wih_f, const float* __restrict__ Whh_f,
                            const float* __restrict__ bih_f, const float* __restrict__ bhh_f,
                            const float* __restrict__ Wih_b, const float* __restrict__ Whh_b,
                            const float* __restrict__ bih_b, const float* __restrict__ bhh_b,
                            float* __restrict__ ws) {
    int tid = blockIdx.x * blockDim.x + threadIdx.x;
    int nth = gridDim.x * blockDim.x;
    float* WihT = ws + OFF_WIHT;
    float* WhhP = ws + OFF_WHHP;
    float* bsum = ws + OFF_BSUM;
    float* hst  = ws + OFF_HST;
    float* cst  = ws + OFF_CST;
    for (int i = tid; i < 2*Dn*NPADn; i += nth) {
        int d = i / (Dn*NPADn); int r = i % (Dn*NPADn); int k = r / NPADn; int g = r % NPADn;
        const float* W = d ? Wih_b : Wih_f;
        WihT[i] = (g < G4n) ? W[(size_t)g*Dn + k] : 0.0f;
    }
    for (int i = tid; i < 2*Hn*G4n; i += nth) {   // WhhP[d][j][k*4+q] = Whh[q*H+k][j]
        int d = i / (Hn*G4n); int r = i % (Hn*G4n);
        int j = r / G4n; int g = r % G4n;
        int k = g >> 2, q = g & 3;
        const float* W = d ? Whh_b : Whh_f;
        WhhP[i] = W[(size_t)(q*Hn + k)*Hn + j];
    }
    for (int i = tid; i < 2*G4n; i += nth) {
        int d = i / G4n; int g = i % G4n;
        bsum[i] = d ? (bih_b[g] + bhh_b[g]) : (bih_f[g] + bhh_f[g]);
    }
    for (int i = tid; i < 2*Bn*Hn; i += nth) { hst[i] = 0.0f; cst[i] = 0.0f; }
}

// ---------------- input projection GEMM for one time-chunk (both dirs) ----------------
// grid: (13 N-tiles, 32 b-pairs, 2 dir), 256 threads; BM=128 (2 b x 64 t), BN=64, BK=16
__global__ __launch_bounds__(256) void gemm_kernel(const float* __restrict__ X,
                                                   float* __restrict__ ws, int chunk) {
    const float* WihT = ws + OFF_WIHT;
    const float* bsum = ws + OFF_BSUM;
    float* G = ws + OFF_G;
    int d = blockIdx.z;
    int bp = blockIdx.y;          // batch pair
    int g0 = blockIdx.x * 64;
    int tid = threadIdx.x;
    int tx = tid % 16, ty = tid / 16;
    int t_base = (d == 0) ? chunk * TCn : (Tn - (chunk + 1) * TCn);
    const float* Bmat = WihT + (size_t)d * Dn * NPADn;

    __shared__ float As[16][136];
    __shared__ float Bs[16][68];
    float acc[8][4] = {{0.f}};
    int lr = tid / 2, lk = tid % 2;   // A load: row in [0,128), k-octet
    int bk = tid / 16, bg = tid % 16; // B load: k row, g-quad
    int a_b = bp * 2 + lr / 64;
    int a_t = t_base + (lr % 64);
    const float* Arow = X + ((size_t)a_b * Tn + a_t) * Dn;

    for (int kt = 0; kt < Dn; kt += 16) {
        float4 a4a = *(const float4*)(Arow + kt + lk * 8);
        float4 a4b = *(const float4*)(Arow + kt + lk * 8 + 4);
        float4 b4  = *(const float4*)(Bmat + (size_t)(kt + bk) * NPADn + g0 + bg * 4);
        __syncthreads();
        As[lk*8+0][lr] = a4a.x; As[lk*8+1][lr] = a4a.y;
        As[lk*8+2][lr] = a4a.z; As[lk*8+3][lr] = a4a.w;
        As[lk*8+4][lr] = a4b.x; As[lk*8+5][lr] = a4b.y;
        As[lk*8+6][lr] = a4b.z; As[lk*8+7][lr] = a4b.w;
        *(float4*)&Bs[bk][bg*4] = b4;
        __syncthreads();
        #pragma unroll
        for (int kk = 0; kk < 16; ++kk) {
            float4 af0 = *(const float4*)&As[kk][ty*8];
            float4 af1 = *(const float4*)&As[kk][ty*8+4];
            float4 bf  = *(const float4*)&Bs[kk][tx*4];
            acc[0][0] += af0.x*bf.x; acc[0][1] += af0.x*bf.y; acc[0][2] += af0.x*bf.z; acc[0][3] += af0.x*bf.w;
            acc[1][0] += af0.y*bf.x; acc[1][1] += af0.y*bf.y; acc[1][2] += af0.y*bf.z; acc[1][3] += af0.y*bf.w;
            acc[2][0] += af0.z*bf.x; acc[2][1] += af0.z*bf.y; acc[2][2] += af0.z*bf.z; acc[2][3] += af0.z*bf.w;
            acc[3][0] += af0.w*bf.x; acc[3][1] += af0.w*bf.y; acc[3][2] += af0.w*bf.z; acc[3][3] += af0.w*bf.w;
            acc[4][0] += af1.x*bf.x; acc[4][1] += af1.x*bf.y; acc[4][2] += af1.x*bf.z; acc[4][3] += af1.x*bf.w;
            acc[5][0] += af1.y*bf.x; acc[5][1] += af1.y*bf.y; acc[5][2] += af1.y*bf.z; acc[5][3] += af1.y*bf.w;
            acc[6][0] += af1.z*bf.x; acc[6][1] += af1.z*bf.y; acc[6][2] += af1.z*bf.z; acc[6][3] += af1.z*bf.w;
            acc[7][0] += af1.w*bf.x; acc[7][1] += af1.w*bf.y; acc[7][2] += af1.w*bf.z; acc[7][3] += af1.w*bf.w;
        }
    }
    #pragma unroll
    for (int ii = 0; ii < 8; ++ii) {
        int r = ty * 8 + ii;
        int b = bp * 2 + r / 64;
        int tloc = r % 64;
        #pragma unroll
        for (int jj = 0; jj < 4; ++jj) {
            int g = g0 + tx * 4 + jj;
            if (g < G4n) {
                int k = g % Hn, q = g / Hn;
                G[(((size_t)d*Bn + b)*TCn + tloc)*G4n + k*4 + q] = acc[ii][jj] + bsum[d*G4n + g];
            }
        }
    }
}

// ---------------- LSTM recurrence: weights resident, (k,q)-parallel activations ----------------
// grid: (64 b, 2 dir) = 128 WGs, 1024 threads = 16 waves.
// Phase A (tid<1000): part=tid/200, k=tid%200 -> gate-quad k over j-slice [part*40,+40):
//   24 j in VGPR/AGPR, 8 in LDS, 8 streamed (loads issued FIRST to hide L2 latency).
// Phase B (tid<800): u=(kk*4+qq); sums 5 partials, ONE activation per thread,
//   3 shfl_xor gather i,f,gg,o at qq==0 owner, who updates h,c and writes hbuf.
// Hcat store: deferred to next step, coalesced by threads 0..199.
__global__ __launch_bounds__(1024, 4) void rec_kernel(const float* __restrict__ mask,
                                                      float* __restrict__ ws, int chunk) {
    const float* G = ws + OFF_G;
    float* Hcat = ws + OFF_HCAT;
    float* hst = ws + OFF_HST;
    float* cst = ws + OFF_CST;
    const float* WP = ws + OFF_WHHP;

    int b = blockIdx.x;
    int d = blockIdx.y;
    int tid = threadIdx.x;
    int k = tid % 200;
    int part = tid / 200;          // 0..5 (part 5: 24 idle threads)
    bool act = (part < 5);
    int qq = tid & 3, kk = tid >> 2;
    bool bact = (tid < 800);

    __shared__ float4 wlds[5][JL][200];   // 125 KiB
    __shared__ float4 partial[5][200];    // 15.6 KiB
    __shared__ float  hbuf[2][208];       // 1.6 KiB

    const float* Wd = WP + (size_t)d * Hn * G4n;
    int base = part * 40;
    float4 wreg[JV];
    if (act) {
        #pragma unroll
        for (int jj = 0; jj < JV; ++jj)
            wreg[jj] = *(const float4*)(Wd + (size_t)(base + jj) * G4n + k * 4);
        #pragma unroll
        for (int jj = 0; jj < JL; ++jj)
            wlds[part][jj][k] = *(const float4*)(Wd + (size_t)(base + JV + jj) * G4n + k * 4);
    }
    size_t soff = ((size_t)d * Bn + b) * Hn;
    float hr = 0.f, cr = 0.f;
    if (bact && qq == 0) {
        hr = hst[soff + kk];
        cr = cst[soff + kk];
    }
    if (tid < 200) hbuf[0][tid] = hst[soff + tid];
    __syncthreads();

    const float* Wst = Wd + (size_t)(base + JV + JL) * G4n + k * 4;
    const float* Grow = G + ((size_t)d * Bn + b) * TCn * G4n;
    const float* mrow = mask + (size_t)b * Tn;
    float* Hrow = Hcat + (size_t)b * Tn * (2 * Hn) + d * Hn;

    int cur = 0;
    for (int s = 0; s < TCn; ++s) {
        int tg, tloc;
        if (d == 0) { tloc = s; tg = chunk * TCn + s; }
        else        { tloc = TCn - 1 - s; tg = Tn - 1 - (chunk * TCn + s); }
        // ---- deferred coalesced Hcat store of previous step's h ----
        if (s > 0 && tid < 200) {
            int tgp = (d == 0) ? (chunk * TCn + s - 1) : (Tn - 1 - (chunk * TCn + s - 1));
            Hrow[(size_t)tgp * (2 * Hn) + tid] = hbuf[cur][tid];
        }
        // ---- B prefetch: 1 float gate-input per thread + mask ----
        float m_ = 0.f, gq = 0.f;
        if (bact) {
            m_ = mrow[tg];
            gq = Grow[(size_t)tloc * G4n + tid];
        }
        // ---- Phase A: gemv ----
        if (act) {
            float4 wstm[8];
            #pragma unroll
            for (int jj = 0; jj < 8; ++jj)   // issue stream loads FIRST
                wstm[jj] = *(const float4*)(Wst + (size_t)jj * G4n);
            float4 acc = {0.f, 0.f, 0.f, 0.f};
            // VGPR/AGPR-resident j: 6 h-quads
            #pragma unroll
            for (int h4 = 0; h4 < 6; ++h4) {
                float4 hv = *(const float4*)&hbuf[cur][base + h4 * 4];
                acc.x += wreg[h4*4+0].x*hv.x; acc.y += wreg[h4*4+0].y*hv.x; acc.z += wreg[h4*4+0].z*hv.x; acc.w += wreg[h4*4+0].w*hv.x;
                acc.x += wreg[h4*4+1].x*hv.y; acc.y += wreg[h4*4+1].y*hv.y; acc.z += wreg[h4*4+1].z*hv.y; acc.w += wreg[h4*4+1].w*hv.y;
                acc.x += wreg[h4*4+2].x*hv.z; acc.y += wreg[h4*4+2].y*hv.z; acc.z += wreg[h4*4+2].z*hv.z; acc.w += wreg[h4*4+2].w*hv.z;
                acc.x += wreg[h4*4+3].x*hv.w; acc.y += wreg[h4*4+3].y*hv.w; acc.z += wreg[h4*4+3].z*hv.w; acc.w += wreg[h4*4+3].w*hv.w;
            }
            // LDS-resident j: 2 h-quads
            #pragma unroll
            for (int h4 = 0; h4 < 2; ++h4) {
                float4 hv = *(const float4*)&hbuf[cur][base + JV + h4 * 4];
                float4 w0 = wlds[part][h4*4+0][k];
                float4 w1 = wlds[part][h4*4+1][k];
                float4 w2 = wlds[part][h4*4+2][k];
                float4 w3 = wlds[part][h4*4+3][k];
                acc.x += w0.x*hv.x; acc.y += w0.y*hv.x; acc.z += w0.z*hv.x; acc.w += w0.w*hv.x;
                acc.x += w1.x*hv.y; acc.y += w1.y*hv.y; acc.z += w1.z*hv.y; acc.w += w1.w*hv.y;
                acc.x += w2.x*hv.z; acc.y += w2.y*hv.z; acc.z += w2.z*hv.z; acc.w += w2.w*hv.z;
                acc.x += w3.x*hv.w; acc.y += w3.y*hv.w; acc.z += w3.z*hv.w; acc.w += w3.w*hv.w;
            }
            // streamed j: 2 h-quads
            #pragma unroll
            for (int h4 = 0; h4 < 2; ++h4) {
                float4 hv = *(const float4*)&hbuf[cur][base + JV + JL + h4 * 4];
                float4 w0 = wstm[h4*4+0];
                float4 w1 = wstm[h4*4+1];
                float4 w2 = wstm[h4*4+2];
                float4 w3 = wstm[h4*4+3];
                acc.x += w0.x*hv.x; acc.y += w0.y*hv.x; acc.z += w0.z*hv.x; acc.w += w0.w*hv.x;
                acc.x += w1.x*hv.y; acc.y += w1.y*hv.y; acc.z += w1.z*hv.y; acc.w += w1.w*hv.y;
                acc.x += w2.x*hv.z; acc.y += w2.y*hv.z; acc.z += w2.z*hv.z; acc.w += w2.w*hv.z;
                acc.x += w3.x*hv.w; acc.y += w3.y*hv.w; acc.z += w3.z*hv.w; acc.w += w3.w*hv.w;
            }
            partial[part][k] = acc;
        }
        __syncthreads();
        // ---- Phase B: per-(k,q) reduce + activation, shuffle-gather at owner ----
        if (bact) {
            const float* pf = (const float*)partial;
            float g = gq + (((pf[0*800 + tid] + pf[1*800 + tid]) +
                             (pf[2*800 + tid] + pf[3*800 + tid])) + pf[4*800 + tid]);
            float arg = (qq == 2) ? 2.f * g : g;
            float sg = 1.f / (1.f + expf(-arg));
            float a = (qq == 2) ? 2.f * sg - 1.f : sg;   // tanh(g) = 2*sig(2g)-1
            float x1 = __shfl_xor(a, 1);
            float x2 = __shfl_xor(a, 2);
            float x3 = __shfl_xor(x1, 2);
            if (qq == 0) {
                float i_ = a, f_ = x1, gg_ = x2, o_ = x3;
                float cn = f_ * cr + i_ * gg_;
                float hn = o_ * tanhf(cn);
                cr = m_ * cn + (1.f - m_) * cr;
                hr = m_ * hn + (1.f - m_) * hr;
                hbuf[cur ^ 1][kk] = hr;
            }
        }
        __syncthreads();
        cur ^= 1;
    }
    // epilogue: last step's Hcat row + carry state
    if (tid < 200) {
        int tgp = (d == 0) ? (chunk * TCn + TCn - 1) : (Tn - 1 - (chunk * TCn + TCn - 1));
        Hrow[(size_t)tgp * (2 * Hn) + tid] = hbuf[cur][tid];
    }
    if (bact && qq == 0) {
        hst[soff + kk] = hr;
        cst[soff + kk] = cr;
    }
}

// ---------------- emissions: E = (Hcat @ Wl^T + bl) * mask ----------------
// grid: 256 WGs x 128 rows each
__global__ __launch_bounds__(256) void emis_kernel(const float* __restrict__ mask,
                                                   const float* __restrict__ Wl,
                                                   const float* __restrict__ bl,
                                                   float* __restrict__ ws) {
    const float* Hcat = ws + OFF_HCAT;
    float* E = ws + OFF_E;
    __shared__ float Wls[Ln * 404];
    __shared__ float Hs[16 * 404];
    int tid = threadIdx.x;
    for (int i = tid; i < Ln * 100; i += 256) {
        int l = i / 100, k4 = i % 100;
        *(float4*)&Wls[l*404 + k4*4] = *(const float4*)(Wl + (size_t)l*Dn + k4*4);
    }
    int rbase = blockIdx.x * 128;
    for (int sub = 0; sub < 8; ++sub) {
        int r0 = rbase + sub * 16;
        __syncthreads();
        for (int i = tid; i < 16 * 100; i += 256) {
            int r = i / 100, k4 = i % 100;
            *(float4*)&Hs[r*404 + k4*4] = *(const float4*)(Hcat + (size_t)(r0 + r)*Dn + k4*4);
        }
        __syncthreads();
        for (int o = tid; o < 16 * Ln; o += 256) {
            int r = o / Ln, l = o % Ln;
            float acc = 0.f;
            #pragma unroll 4
            for (int k4 = 0; k4 < 100; ++k4) {
                float4 h = *(const float4*)&Hs[r*404 + k4*4];
                float4 wv = *(const float4*)&Wls[l*404 + k4*4];
                acc += h.x*wv.x + h.y*wv.y + h.z*wv.z + h.w*wv.w;
            }
            int row = r0 + r;            // row == b*T + t
            float m = mask[row];
            E[(size_t)row * Ln + l] = (acc + bl[l]) * m;
        }
    }
}

// ---------------- fused CRF-forward + Viterbi: 128 one-wave blocks ----------------
__global__ __launch_bounds__(64) void decode_kernel(const float* __restrict__ mask,
                                                    const int* __restrict__ labels,
                                                    const float* __restrict__ trans,
                                                    const float* __restrict__ start,
                                                    const float* __restrict__ endv,
                                                    float* __restrict__ ws,
                                                    float* __restrict__ out) {
    int role = blockIdx.x >> 6;
    int b = blockIdx.x & 63;
    int l = threadIdx.x;
    const float* E = ws + OFF_E;
    float* part = ws + OFF_PART;

    __shared__ __align__(16) float Es[Tn * Ln];     // 51200 B
    __shared__ __align__(16) float ms[Tn];          // 2048 B
    __shared__ float trs[Ln * Ln];                  // 2500 B
    __shared__ __align__(16) float als[32];
    __shared__ unsigned char ptrs[Tn][Ln];          // 12800 B (vit only)
    __shared__ unsigned char ys[Tn];                // 512 B  (vit only)

    {   // stage E row, mask row, trans (single wave: ordering via lgkmcnt)
        const float4* src = (const float4*)(E + (size_t)b * Tn * Ln);
        float4* dst = (float4*)Es;
        for (int i = l; i < Tn * Ln / 4; i += 64) dst[i] = src[i];
        const float4* msrc = (const float4*)(mask + (size_t)b * Tn);
        float4* mdst = (float4*)ms;
        for (int i = l; i < Tn / 4; i += 64) mdst[i] = msrc[i];
        for (int i = l; i < Ln * Ln; i += 64) trs[i] = trans[i];
    }
    // sequence length (mask is 1s then 0s)
    float cnt = 0.f;
    for (int t = l; t < Tn; t += 64) cnt += mask[(size_t)b * Tn + t];
    for (int off = 32; off; off >>= 1) cnt += __shfl_xor(cnt, off);
    int len = (int)(cnt + 0.5f);

    // per-lane trans column: trc[j] = trans[j][l]; pads -1e30
    float trc[32];
    #pragma unroll
    for (int j = 0; j < 32; ++j) trc[j] = -1e30f;
    if (l < Ln) {
        for (int j = 0; j < Ln; ++j) trc[j] = trans[j * Ln + l];
    }
    __syncthreads();

    if (role == 0) {
        // ---- CRF forward ----
        float alpha = -1e30f;
        if (l < Ln) alpha = start[l] + Es[l];
        if (l < 32) als[l] = (l < Ln) ? alpha : -1e30f;
        for (int t = 1; t < len; ++t) {
            float av[32];
            {
                const float4* ap = (const float4*)als;
                #pragma unroll
                for (int q = 0; q < 8; ++q) {
                    float4 a = ap[q];
                    av[q*4+0] = a.x; av[q*4+1] = a.y; av[q*4+2] = a.z; av[q*4+3] = a.w;
                }
            }
            float v[32];
            #pragma unroll
            for (int j = 0; j < 32; ++j) v[j] = av[j] + trc[j];
            float r[16];
            #pragma unroll
            for (int j = 0; j < 16; ++j) r[j] = fmaxf(v[j], v[j+16]);
            #pragma unroll
            for (int j = 0; j < 8; ++j) r[j] = fmaxf(r[j], r[j+8]);
            #pragma unroll
            for (int j = 0; j < 4; ++j) r[j] = fmaxf(r[j], r[j+4]);
            float mx = fmaxf(fmaxf(r[0], r[1]), fmaxf(r[2], r[3]));
            float e[32];
            #pragma unroll
            for (int j = 0; j < 32; ++j) e[j] = __expf(v[j] - mx);
            #pragma unroll
            for (int j = 0; j < 16; ++j) e[j] += e[j+16];
            #pragma unroll
            for (int j = 0; j < 8; ++j) e[j] += e[j+8];
            #pragma unroll
            for (int j = 0; j < 4; ++j) e[j] += e[j+4];
            float s = (e[0] + e[1]) + (e[2] + e[3]);
            float nv = mx + __logf(s) + Es[t * Ln + l];
            if (l < Ln) { als[l] = nv; alpha = nv; }
        }
        // logZ
        float vfin = (l < Ln) ? alpha + endv[l] : -1e30f;
        float mxf = vfin;
        for (int off = 32; off; off >>= 1) mxf = fmaxf(mxf, __shfl_xor(mxf, off));
        float sf = (l < Ln) ? __expf(vfin - mxf) : 0.f;
        for (int off = 32; off; off >>= 1) sf += __shfl_xor(sf, off);
        float logZ = mxf + __logf(sf);
        // numerator
        float psum = 0.f;
        for (int t = l; t < len; t += 64) {
            if (t >= 1) {
                int lt = labels[(size_t)b * Tn + t];
                int lp = labels[(size_t)b * Tn + t - 1];
                psum += Es[t * Ln + lt] + trs[lp * Ln + lt];
            }
        }
        for (int off = 32; off; off >>= 1) psum += __shfl_xor(psum, off);
        if (l == 0) {
            int l0 = labels[(size_t)b * Tn];
            int yl = labels[(size_t)b * Tn + len - 1];
            part[b] = start[l0] + Es[l0] + psum + endv[yl] - logZ;
        }
    } else {
        // ---- Viterbi ----
        float delta = (l < Ln) ? start[l] + Es[l] : -1e30f;
        if (l < 32) als[l] = (l < Ln) ? delta : -1e30f;
        for (int t = 1; t < len; ++t) {
            float av[32];
            {
                const float4* ap = (const float4*)als;
                #pragma unroll
                for (int q = 0; q < 8; ++q) {
                    float4 a = ap[q];
                    av[q*4+0] = a.x; av[q*4+1] = a.y; av[q*4+2] = a.z; av[q*4+3] = a.w;
                }
            }
            float best = -1e30f; int ba = 0;
            #pragma unroll
            for (int j = 0; j < Ln; ++j) {
                float c = av[j] + trc[j];
                if (c > best) { best = c; ba = j; }   // strict >: first-max (jnp.argmax)
            }
            float nd = best + Es[t * Ln + l];
            if (l < Ln) { als[l] = nd; ptrs[t][l] = (unsigned char)ba; delta = nd; }
        }
        (void)delta;
        float av[32];
        {
            const float4* ap = (const float4*)als;
            #pragma unroll
            for (int q = 0; q < 8; ++q) {
                float4 a = ap[q];
                av[q*4+0] = a.x; av[q*4+1] = a.y; av[q*4+2] = a.z; av[q*4+3] = a.w;
            }
        }
        float bb = -1e30f; int y = 0;
        for (int j = 0; j < Ln; ++j) {
            float c = av[j] + endv[j];
            if (c > bb) { bb = c; y = j; }
        }
        if (l == 0) {
            ys[len - 1] = (unsigned char)y;
            int yy = y;
            for (int t = len - 1; t >= 1; --t) { yy = ptrs[t][yy]; ys[t - 1] = (unsigned char)yy; }
        }
        for (int t = l; t < Tn; t += 64) {
            out[1 + (size_t)b * Tn + t] = (t < len) ? (float)ys[t] : 0.f;
        }
    }
}

// ---------------- finalize loss ----------------
__global__ __launch_bounds__(64) void fin_kernel(float* __restrict__ ws, float* __restrict__ out) {
    const float* part = ws + OFF_PART;
    int l = threadIdx.x;
    float v = (l < Bn) ? part[l] : 0.f;
    for (int off = 32; off; off >>= 1) v += __shfl_xor(v, off);
    if (l == 0) out[0] = -v / (float)Bn;
}

extern "C" void kernel_launch(void* const* d_in, const int* in_sizes, int n_in,
                              void* d_out, int out_size, void* d_ws, size_t ws_size,
                              hipStream_t stream) {
    (void)in_sizes; (void)n_in; (void)out_size; (void)ws_size;
    const float* X      = (const float*)d_in[0];
    const float* mask   = (const float*)d_in[1];
    const int*   labels = (const int*)d_in[2];
    const float* Wih_f  = (const float*)d_in[3];
    const float* Whh_f  = (const float*)d_in[4];
    const float* bih_f  = (const float*)d_in[5];
    const float* bhh_f  = (const float*)d_in[6];
    const float* Wih_b  = (const float*)d_in[7];
    const float* Whh_b  = (const float*)d_in[8];
    const float* bih_b  = (const float*)d_in[9];
    const float* bhh_b  = (const float*)d_in[10];
    const float* Wl     = (const float*)d_in[11];
    const float* bl     = (const float*)d_in[12];
    const float* trans  = (const float*)d_in[13];
    const float* start  = (const float*)d_in[14];
    const float* endv   = (const float*)d_in[15];
    float* ws  = (float*)d_ws;
    float* out = (float*)d_out;

    prep_kernel<<<128, 256, 0, stream>>>(Wih_f, Whh_f, bih_f, bhh_f,
                                         Wih_b, Whh_b, bih_b, bhh_b, ws);
    for (int c = 0; c < NCH; ++c) {
        gemm_kernel<<<dim3(13, 32, 2), 256, 0, stream>>>(X, ws, c);
        rec_kernel<<<dim3(Bn, 2), 1024, 0, stream>>>(mask, ws, c);
    }
    emis_kernel<<<256, 256, 0, stream>>>(mask, Wl, bl, ws);
    decode_kernel<<<128, 64, 0, stream>>>(mask, labels, trans, start, endv, ws, out);
    fin_kernel<<<1, 64, 0, stream>>>(ws, out);
}